// Round 5
// baseline (1899.139 us; speedup 1.0000x reference)
//
#include <hip/hip_runtime.h>

// Problem constants
#define Bz 2048
#define Tz 336
#define Fz 10
#define H1 70
#define H2 21

typedef __attribute__((ext_vector_type(8))) short short8;   // 8 bf16 = 4 VGPR
typedef __attribute__((ext_vector_type(4))) float float4v;  // MFMA acc

#define MFMA16(a, b, c) __builtin_amdgcn_mfma_f32_16x16x32_bf16((a), (b), (c), 0, 0, 0)

// LDS-only barrier (composable-kernel idiom): orders LDS across the block
// WITHOUT draining vmcnt — __syncthreads() would stall on the y1/y2 global
// stores (never read in-kernel) every step (~200-900 cyc store-ack, m126).
__device__ __forceinline__ void sync_lds() {
    asm volatile("s_waitcnt lgkmcnt(0)\n\ts_barrier" ::: "memory");
}

__device__ __forceinline__ float sigf(float x) {
    return 1.0f / (1.0f + __expf(-x));
}
__device__ __forceinline__ float tanhfast(float x) {
    float t = __expf(2.0f * x);
    return 1.0f - 2.0f / (t + 1.0f);
}
__device__ __forceinline__ unsigned short f2bf(float v) {
    unsigned int u = __float_as_uint(v);
    u += 0x7FFFu + ((u >> 16) & 1u);
    return (unsigned short)(u >> 16);
}
__device__ __forceinline__ float bf2f(unsigned short s) {
    return __uint_as_float(((unsigned int)s) << 16);
}

// Fragment-order LDS offset (in shorts) for (col m, k):
// (m, k) lives at ((k>>3)*16 + m)*8 + (k&7)
__device__ __forceinline__ int frag_off(int m, int k) {
    return (k >> 3) * 128 + m * 8 + (k & 7);
}

// ---------------------------------------------------------------------------
// Layer 1 (MFMA, D = W x h): input F=10, hidden 70.
// [round-12 structure: 8-batch chains, 2 blocks/CU for latency overlap]
// Grid 512 = 2 dir x 256 tiles of 8 batch rows. 1024 threads = 16 waves.
// Rationale: kernel is latency-bound (per-SIMD MFMA 4% + VALU 18%); with
// 16-batch tiles there are exactly 256 chains = 1/CU -> nothing hides the
// per-step serial path. 8-batch tiles give 512 chains = 2 co-resident
// blocks/CU whose barrier-locked phases interleave. MFMA B-columns 8..15
// are zero ghosts (stores guarded by n<8); per-row math is bit-identical.
// 18 M-tiles: wave w owns tile w; waves 0,1 also own tiles 16,17.
//   K: 0..69 = h, 70..79 = x, 80 = bias slot (B col 1.0), 81..95 = 0.
// h bf16 hi-only in LDS; W hi+lo in registers (6 MFMA/tile). ONE LDS-only
// barrier per step (sync_lds), double-buffered B-LDS, x prefetch depth 2,
// step loop unrolled x2 (pp literal), strided pointers.
// y1 layout: [T][256][140][8] bf16.
// ---------------------------------------------------------------------------
__global__ __launch_bounds__(1024, 8) void k_lstm1(
    const float* __restrict__ x,
    const float* __restrict__ wih_f, const float* __restrict__ whh_f,
    const float* __restrict__ bih_f, const float* __restrict__ bhh_f,
    const float* __restrict__ wih_b, const float* __restrict__ whh_b,
    const float* __restrict__ bih_b, const float* __restrict__ bhh_b,
    unsigned short* __restrict__ y1)
{
    __shared__ short hB_hi[2][1536];   // 96 k x 16 batch, frag order, dbuf

    const int tb  = blockIdx.x & 255;
    const int dir = blockIdx.x >> 8;
    const int b0  = tb << 3;
    const float* wih = dir ? wih_b : wih_f;
    const float* whh = dir ? whh_b : whh_f;
    const float* bih = dir ? bih_b : bih_f;
    const float* bhh = dir ? bhh_b : bhh_f;

    const int tid  = threadIdx.x;
    const int wv   = tid >> 6;
    const int lane = tid & 63;
    const int n    = lane & 15;
    const int quad = lane >> 4;
    const int NT1  = (wv < 2) ? 2 : 1;   // tiles this wave owns

    // ---- W-side (A-operand) preload, hi+lo bf16 ----
    short8 whi[2][3], wlo[2][3];
    const int g_ = n & 3;
#pragma unroll
    for (int tt = 0; tt < 2; ++tt) {
        if (tt < NT1) {
            const int p  = wv + 16 * tt;
            const int uu = 4 * p + (n >> 2);
#pragma unroll
            for (int q = 0; q < 3; ++q) {
#pragma unroll
                for (int j = 0; j < 8; ++j) {
                    int k = q * 32 + quad * 8 + j;
                    float v = 0.0f;
                    if (uu < H1) {
                        int row = g_ * H1 + uu;
                        if (k < H1)        v = whh[row * H1 + k];
                        else if (k < 80)   v = wih[row * Fz + (k - H1)];
                        else if (k == 80)  v = bih[row] + bhh[row];
                    }
                    unsigned short hi = f2bf(v);
                    unsigned short lo = f2bf(v - bf2f(hi));
                    whi[tt][q][j] = (short)hi;
                    wlo[tt][q][j] = (short)lo;
                }
            }
        }
    }

    // ---- init LDS ----
    for (int e = tid; e < 1536; e += 1024) {
        hB_hi[0][e] = 0; hB_hi[1][e] = 0;
    }
    __syncthreads();
    if (tid < 8) {                      // bias col only for the 8 real batches
        int off = 1280 + tid * 8;       // frag_off(tid, 80)
        hB_hi[0][off] = (short)0x3F80;  // bf16(1.0) bias const
        hB_hi[1][off] = (short)0x3F80;
    }

    // ---- stagers: es in [0,80) -> (m, f), threads 944..1023 ----
    const int es = tid - 944;
    const bool stg = (es >= 0 && es < 80);
    int sm = 0, sf = 0;
    if (stg) { sm = es / Fz; sf = es % Fz; }

    const int tstep = dir ? -1 : 1;
    const int t0    = dir ? (Tz - 1) : 0;

    // prologue: stage x(t0) into buf 0; preload x(t1) into regs
    float xv = 0.0f;
    if (stg) {
        float v = x[((size_t)(b0 + sm) * Tz + t0) * Fz + sf];
        hB_hi[0][frag_off(sm, H1 + sf)] = (short)f2bf(v);
        xv = x[((size_t)(b0 + sm) * Tz + t0 + tstep) * Fz + sf];
    }
    // strided pointers (advance by tstep*stride per step)
    const float* xp = x + ((size_t)(b0 + sm) * Tz + t0 + 2 * tstep) * Fz + sf;
    const ptrdiff_t xinc = (ptrdiff_t)tstep * Fz;
    unsigned short* yp = y1 + (((size_t)t0 * 256 + tb) * 140 + dir * H1) * 8 + n;
    const ptrdiff_t yinc = (ptrdiff_t)tstep * (140 * 256 * 8);

    // hoisted LDS write offsets (loop-invariant)
    const int xoff = frag_off(sm, H1 + sf);
    int hoff[2];
#pragma unroll
    for (int tt = 0; tt < 2; ++tt) hoff[tt] = frag_off(n, 4 * (wv + 16 * tt) + quad);

    float cst[2];
    cst[0] = 0.0f; cst[1] = 0.0f;

    // one step; pp is a literal at each call site -> all LDS addrs invariant
    auto body = [&](int step, const int pp) __attribute__((always_inline)) {
        sync_lds();   // buf[pp] complete, buf[pp^1] free (LDS-only barrier)

        if (stg && step + 1 < Tz) {
            hB_hi[pp ^ 1][xoff] = (short)f2bf(xv);
        }
        if (stg && step + 2 < Tz) {
            xv = *xp;
        }

        short8 bhi[3];
#pragma unroll
        for (int q = 0; q < 3; ++q)
            bhi[q] = *(const short8*)&hB_hi[pp][q * 512 + lane * 8];

        float4v accA[2], accB[2];
#pragma unroll
        for (int tt = 0; tt < 2; ++tt) {
            accA[tt] = (float4v){0.f, 0.f, 0.f, 0.f};
            accB[tt] = (float4v){0.f, 0.f, 0.f, 0.f};
        }
#pragma unroll
        for (int tt = 0; tt < 2; ++tt) {
            if (tt < NT1) {
                accA[tt] = MFMA16(whi[tt][0], bhi[0], accA[tt]);
                accB[tt] = MFMA16(wlo[tt][0], bhi[0], accB[tt]);
                accA[tt] = MFMA16(whi[tt][1], bhi[1], accA[tt]);
                accB[tt] = MFMA16(wlo[tt][1], bhi[1], accB[tt]);
                accA[tt] = MFMA16(whi[tt][2], bhi[2], accA[tt]);
                accB[tt] = MFMA16(wlo[tt][2], bhi[2], accB[tt]);
            }
        }

#pragma unroll
        for (int tt = 0; tt < 2; ++tt) {
            if (tt < NT1) {
                const int u = 4 * (wv + 16 * tt) + quad;
                if (u < H1) {
                    float gi = accA[tt][0] + accB[tt][0];
                    float gf = accA[tt][1] + accB[tt][1];
                    float gc = accA[tt][2] + accB[tt][2];
                    float go = accA[tt][3] + accB[tt][3];
                    float cn = sigf(gf) * cst[tt] + sigf(gi) * tanhfast(gc);
                    float h  = sigf(go) * tanhfast(cn);
                    cst[tt] = cn;
                    unsigned short hh = f2bf(h);
                    if (n < 8) {   // cols 8..15 are zero ghosts: never stored
                        hB_hi[pp ^ 1][hoff[tt]] = (short)hh;
                        yp[u * 8] = hh;
                    }
                }
            }
        }
        xp += xinc;
        yp += yinc;
    };

    for (int step = 0; step < Tz; step += 2) {
        body(step, 0);
        body(step + 1, 1);
    }
}

// ---------------------------------------------------------------------------
// Layer 2 (MFMA, D = W x h): input 140 (bf16 y1 [T][256][140][8]), hidden 21.
// [round-12 structure: 8-batch chains, 2 blocks/CU] Grid 512 = 2 dir x 256
// tiles of 8 rows. 512 thr = 8 waves: waves 0..5 compute tile p = wv
// (u = 4p+quad); threads 372..511 stage x (16B vector loads: one short8 =
// 8 batch cols of one feature). K: 0..20 = h, 21 = bias, 32..171 = x.
// h/x hi-only; W-lo for chunk 0 only: 7 MFMA/wave. LDS-only barrier.
// ---------------------------------------------------------------------------
__global__ __launch_bounds__(512, 4) void k_lstm2(
    const unsigned short* __restrict__ y1,
    const float* __restrict__ wih_f, const float* __restrict__ whh_f,
    const float* __restrict__ bih_f, const float* __restrict__ bhh_f,
    const float* __restrict__ wih_b, const float* __restrict__ whh_b,
    const float* __restrict__ bih_b, const float* __restrict__ bhh_b,
    unsigned short* __restrict__ y2)   // [B][T][42] bf16
{
    __shared__ short hB_hi[2][3072];   // 192 k x 16 batch

    const int tb  = blockIdx.x & 255;
    const int dir = blockIdx.x >> 8;
    const int b0  = tb << 3;
    const float* wih = dir ? wih_b : wih_f;
    const float* whh = dir ? whh_b : whh_f;
    const float* bih = dir ? bih_b : bih_f;
    const float* bhh = dir ? bhh_b : bhh_f;

    const int tid  = threadIdx.x;
    const int wv   = tid >> 6;
    const int lane = tid & 63;
    const int n    = lane & 15;
    const int quad = lane >> 4;
    const bool comp = (wv < 6);

    // ---- W-side preload (waves 0..5): hi all chunks, lo chunk 0 ----
    short8 whi[6], wlo0;
    const int g_ = n & 3;
    if (comp) {
        const int uu = 4 * wv + (n >> 2);
#pragma unroll
        for (int q = 0; q < 6; ++q) {
#pragma unroll
            for (int j = 0; j < 8; ++j) {
                int k = q * 32 + quad * 8 + j;
                float v = 0.0f;
                if (uu < H2) {
                    int row = g_ * H2 + uu;
                    if (k < H2)                   v = whh[row * H2 + k];
                    else if (k == 21)             v = bih[row] + bhh[row];
                    else if (k >= 32 && k < 172)  v = wih[row * 140 + (k - 32)];
                }
                unsigned short hi = f2bf(v);
                whi[q][j] = (short)hi;
                if (q == 0) wlo0[j] = (short)f2bf(v - bf2f(hi));
            }
        }
    }

    // ---- init LDS ----
    for (int e = tid; e < 3072; e += 512) { hB_hi[0][e] = 0; hB_hi[1][e] = 0; }
    __syncthreads();
    if (tid < 8) {
        int off = frag_off(tid, 21);
        hB_hi[0][off] = (short)0x3F80;   // bias const 1.0
        hB_hi[1][off] = (short)0x3F80;
    }

    // ---- stager threads: es in [0,140); each loads 16B = feature es, n 0..7
    const int es = tid - 372;
    const bool stg = (es >= 0 && es < 140);

    const int tstep = dir ? -1 : 1;
    const int t0    = dir ? (Tz - 1) : 0;

    // prologue: stage x(t0) into buf 0; preload x(t1)
    short8 xr = (short8){0,0,0,0,0,0,0,0};
    if (stg) {
        short8 v = *(const short8*)(y1 + ((size_t)t0 * 256 + tb) * 1120 + es * 8);
#pragma unroll
        for (int j = 0; j < 8; ++j)
            hB_hi[0][frag_off(j, 32 + es)] = v[j];
        xr = *(const short8*)(y1 + ((size_t)(t0 + tstep) * 256 + tb) * 1120 + es * 8);
    }
    // strided pointers
    const unsigned short* srcp =
        y1 + ((size_t)(t0 + 2 * tstep) * 256 + tb) * 1120 + es * 8;
    const ptrdiff_t sinc = (ptrdiff_t)tstep * (256 * 1120);
    unsigned short* yp2 = y2 + ((size_t)(b0 + n) * Tz + t0) * 42 + dir * H2;
    const ptrdiff_t yinc = (ptrdiff_t)tstep * 42;

    // hoisted LDS offsets
    int xoffs[8];
#pragma unroll
    for (int j = 0; j < 8; ++j) {
        xoffs[j] = frag_off(j, 32 + es);
    }
    const int u     = 4 * wv + quad;
    const int hoffc = frag_off(n, (u < H2) ? u : 0);

    float cst = 0.0f;

    auto body = [&](int step, const int pp) __attribute__((always_inline)) {
        sync_lds();   // LDS-only barrier

        if (stg && step + 1 < Tz) {
#pragma unroll
            for (int j = 0; j < 8; ++j)
                hB_hi[pp ^ 1][xoffs[j]] = xr[j];
        }
        if (stg && step + 2 < Tz) {
            xr = *(const short8*)srcp;
        }

        if (comp) {
            short8 bhi[6];
#pragma unroll
            for (int q = 0; q < 6; ++q)
                bhi[q] = *(const short8*)&hB_hi[pp][q * 512 + lane * 8];

            float4v accA = (float4v){0.f, 0.f, 0.f, 0.f};
            float4v accB = (float4v){0.f, 0.f, 0.f, 0.f};
            accA = MFMA16(whi[0], bhi[0], accA);
            accB = MFMA16(wlo0,   bhi[0], accB);
            accA = MFMA16(whi[2], bhi[2], accA);
            accB = MFMA16(whi[1], bhi[1], accB);
            accA = MFMA16(whi[4], bhi[4], accA);
            accB = MFMA16(whi[3], bhi[3], accB);
            accB = MFMA16(whi[5], bhi[5], accB);

            if (u < H2) {
                float gi = accA[0] + accB[0];
                float gf = accA[1] + accB[1];
                float gc = accA[2] + accB[2];
                float go = accA[3] + accB[3];
                float cn = sigf(gf) * cst + sigf(gi) * tanhfast(gc);
                float h  = sigf(go) * tanhfast(cn);
                cst = cn;
                unsigned short hh = f2bf(h);
                if (n < 8) {   // cols 8..15 are zero ghosts: never stored
                    hB_hi[pp ^ 1][hoffc] = (short)hh;
                    yp2[u] = hh;
                }
            }
        }
        srcp += sinc;
        yp2  += yinc;
    };

    for (int step = 0; step < Tz; step += 2) {
        body(step, 0);
        body(step + 1, 1);
    }
}

// ---------------------------------------------------------------------------
// Dense head: thread per (b,t). Weights via uniform scalar loads.
// ---------------------------------------------------------------------------
__global__ __launch_bounds__(256) void k_dense(
    const unsigned short* __restrict__ y2,
    const float* __restrict__ wd1, const float* __restrict__ bd1,
    const float* __restrict__ wd2, const float* __restrict__ bd2,
    const float* __restrict__ wo,  const float* __restrict__ bo,
    float* __restrict__ out)
{
    int idx = blockIdx.x * 256 + threadIdx.x;
    if (idx >= Bz * Tz) return;
    const unsigned int* row = (const unsigned int*)&y2[(size_t)idx * 42];

    float v[42];
#pragma unroll
    for (int j = 0; j < 21; ++j) {
        unsigned int p = row[j];
        v[2 * j]     = bf2f((unsigned short)(p & 0xFFFFu));
        v[2 * j + 1] = bf2f((unsigned short)(p >> 16));
    }

    float h1[30];
#pragma unroll
    for (int o = 0; o < 30; ++o) {
        float s = bd1[o];
#pragma unroll
        for (int j = 0; j < 42; ++j) s = fmaf(v[j], wd1[o * 42 + j], s);
        h1[o] = fmaxf(s, 0.0f);
    }
    float outv = bo[0];
#pragma unroll
    for (int o = 0; o < 20; ++o) {
        float s = bd2[o];
#pragma unroll
        for (int j = 0; j < 30; ++j) s = fmaf(h1[j], wd2[o * 30 + j], s);
        outv = fmaf(fmaxf(s, 0.0f), wo[o], outv);
    }
    out[idx] = outv;
}

// ---------------------------------------------------------------------------
extern "C" void kernel_launch(void* const* d_in, const int* in_sizes, int n_in,
                              void* d_out, int out_size, void* d_ws, size_t ws_size,
                              hipStream_t stream)
{
    const float* x      = (const float*)d_in[0];
    const float* w1f_ih = (const float*)d_in[1];
    const float* w1f_hh = (const float*)d_in[2];
    const float* b1f_ih = (const float*)d_in[3];
    const float* b1f_hh = (const float*)d_in[4];
    const float* w1b_ih = (const float*)d_in[5];
    const float* w1b_hh = (const float*)d_in[6];
    const float* b1b_ih = (const float*)d_in[7];
    const float* b1b_hh = (const float*)d_in[8];
    const float* w2f_ih = (const float*)d_in[9];
    const float* w2f_hh = (const float*)d_in[10];
    const float* b2f_ih = (const float*)d_in[11];
    const float* b2f_hh = (const float*)d_in[12];
    const float* w2b_ih = (const float*)d_in[13];
    const float* w2b_hh = (const float*)d_in[14];
    const float* b2b_ih = (const float*)d_in[15];
    const float* b2b_hh = (const float*)d_in[16];
    const float* wd1    = (const float*)d_in[17];
    const float* bd1    = (const float*)d_in[18];
    const float* wd2    = (const float*)d_in[19];
    const float* bd2    = (const float*)d_in[20];
    const float* wo     = (const float*)d_in[21];
    const float* bo     = (const float*)d_in[22];
    float* out = (float*)d_out;

    // Workspace: y1 bf16 [T][256][140][8] (192.7 MB) + y2 bf16 [B][T][42] (57.8 MB)
    const size_t y1_elems = (size_t)Tz * 256 * 1120;
    const size_t y2_elems = (size_t)Bz * Tz * 42;
    if (ws_size < (y1_elems + y2_elems) * 2) return;

    unsigned short* y1 = (unsigned short*)d_ws;
    unsigned short* y2 = y1 + y1_elems;

    hipLaunchKernelGGL(k_lstm1, dim3(512), dim3(1024), 0, stream,
                       x, w1f_ih, w1f_hh, b1f_ih, b1f_hh,
                       w1b_ih, w1b_hh, b1b_ih, b1b_hh, y1);
    hipLaunchKernelGGL(k_lstm2, dim3(512), dim3(512), 0, stream,
                       y1, w2f_ih, w2f_hh, b2f_ih, b2f_hh,
                       w2b_ih, w2b_hh, b2b_ih, b2b_hh, y2);
    hipLaunchKernelGGL(k_dense, dim3((Bz * Tz + 255) / 256), dim3(256), 0, stream,
                       y2, wd1, bd1, wd2, bd2, wo, bo, out);
}

// Round 9
// 808.353 us; speedup vs baseline: 2.3494x; 2.3494x over previous
//
#include <hip/hip_runtime.h>

// Problem constants
#define Bz 2048
#define Tz 336
#define Fz 10
#define H1 70
#define H2 21

typedef __attribute__((ext_vector_type(8))) short short8;   // 8 bf16 = 4 VGPR
typedef __attribute__((ext_vector_type(4))) float float4v;  // MFMA acc

#define MFMA16(a, b, c) __builtin_amdgcn_mfma_f32_16x16x32_bf16((a), (b), (c), 0, 0, 0)

// LDS-only barrier (composable-kernel idiom): orders LDS across the block
// WITHOUT draining vmcnt — __syncthreads() would stall on the y1/y2 global
// stores (never read in-kernel) every step (~200-900 cyc store-ack, m126).
__device__ __forceinline__ void sync_lds() {
    asm volatile("s_waitcnt lgkmcnt(0)\n\ts_barrier" ::: "memory");
}

__device__ __forceinline__ float sigf(float x) {
    return 1.0f / (1.0f + __expf(-x));
}
__device__ __forceinline__ float tanhfast(float x) {
    float t = __expf(2.0f * x);
    return 1.0f - 2.0f / (t + 1.0f);
}
__device__ __forceinline__ unsigned short f2bf(float v) {
    unsigned int u = __float_as_uint(v);
    u += 0x7FFFu + ((u >> 16) & 1u);
    return (unsigned short)(u >> 16);
}
__device__ __forceinline__ float bf2f(unsigned short s) {
    return __uint_as_float(((unsigned int)s) << 16);
}

// Fragment-order LDS offset (in shorts) for (col m, k):
// (m, k) lives at ((k>>3)*16 + m)*8 + (k&7)
__device__ __forceinline__ int frag_off(int m, int k) {
    return (k >> 3) * 128 + m * 8 + (k & 7);
}

// ---------------------------------------------------------------------------
// Layer 1 (MFMA, D = W x h): input F=10, hidden 70.
// [round-13 structure: 6 balanced waves, shortest per-step critical path]
// Post-mortem r5: launch_bounds(1024,8) forced VGPR 56->32, weights spilled
// to scratch (FETCH 25.6->844 MB, dur 415->1522us). Also: co-resident twin
// chains can't shorten wall time (each block still runs 336 serial steps).
// This round: attack the per-step path instead. 16-wave block had (a) 1
// barrier/step over 16 waves (skew), (b) waves 0,1 owning 2 tiles = everyone
// waits for stragglers, (c) stager waves stacked on compute waves.
// Now: 384 threads = 6 waves, 18 M-tiles = 6 waves x 3 tiles (EXACT balance).
// Grid 256 = 2 dir x 128 tiles of 16 batch rows (full MFMA N-use, 1 blk/CU).
//   K: 0..69 = h, 70..79 = x, 80 = bias slot (B col 1.0), 81..95 = 0.
// h bf16 hi-only in LDS; W hi+lo in registers (6 MFMA/tile, 18/wave). ONE
// LDS-only barrier per step, double-buffered B-LDS, x prefetch depth 2,
// step loop unrolled x2 (pp literal), strided pointers.
// y1 layout: [T][128][140][16] bf16.
// ---------------------------------------------------------------------------
__global__ __launch_bounds__(384, 2) void k_lstm1(
    const float* __restrict__ x,
    const float* __restrict__ wih_f, const float* __restrict__ whh_f,
    const float* __restrict__ bih_f, const float* __restrict__ bhh_f,
    const float* __restrict__ wih_b, const float* __restrict__ whh_b,
    const float* __restrict__ bih_b, const float* __restrict__ bhh_b,
    unsigned short* __restrict__ y1)
{
    __shared__ short hB_hi[2][1536];   // 96 k x 16 batch, frag order, dbuf

    const int tb  = blockIdx.x & 127;
    const int dir = blockIdx.x >> 7;
    const int b0  = tb << 4;
    const float* wih = dir ? wih_b : wih_f;
    const float* whh = dir ? whh_b : whh_f;
    const float* bih = dir ? bih_b : bih_f;
    const float* bhh = dir ? bhh_b : bhh_f;

    const int tid  = threadIdx.x;
    const int wv   = tid >> 6;          // 0..5
    const int lane = tid & 63;
    const int n    = lane & 15;
    const int quad = lane >> 4;

    // ---- W-side (A-operand) preload, hi+lo bf16: tiles p = wv + 6*tt ----
    short8 whi[3][3], wlo[3][3];        // 18 short8 = 72 VGPR
    const int g_ = n & 3;
#pragma unroll
    for (int tt = 0; tt < 3; ++tt) {
        const int p  = wv + 6 * tt;
        const int uu = 4 * p + (n >> 2);
#pragma unroll
        for (int q = 0; q < 3; ++q) {
#pragma unroll
            for (int j = 0; j < 8; ++j) {
                int k = q * 32 + quad * 8 + j;
                float v = 0.0f;
                if (uu < H1) {
                    int row = g_ * H1 + uu;
                    if (k < H1)        v = whh[row * H1 + k];
                    else if (k < 80)   v = wih[row * Fz + (k - H1)];
                    else if (k == 80)  v = bih[row] + bhh[row];
                }
                unsigned short hi = f2bf(v);
                unsigned short lo = f2bf(v - bf2f(hi));
                whi[tt][q][j] = (short)hi;
                wlo[tt][q][j] = (short)lo;
            }
        }
    }

    // ---- init LDS ----
    for (int e = tid; e < 1536; e += 384) {
        hB_hi[0][e] = 0; hB_hi[1][e] = 0;
    }
    __syncthreads();
    if (tid < 16) {
        int off = 1280 + tid * 8;       // frag_off(tid, 80)
        hB_hi[0][off] = (short)0x3F80;  // bf16(1.0) bias const
        hB_hi[1][off] = (short)0x3F80;
    }

    // ---- stagers: es in [0,160) -> (m, f); spread over waves 0..2 ----
    const int es = tid;
    const bool stg = (es < 160);
    int sm = 0, sf = 0;
    if (stg) { sm = es / Fz; sf = es % Fz; }

    const int tstep = dir ? -1 : 1;
    const int t0    = dir ? (Tz - 1) : 0;

    // prologue: stage x(t0) into buf 0; preload x(t1) into regs
    float xv = 0.0f;
    if (stg) {
        float v = x[((size_t)(b0 + sm) * Tz + t0) * Fz + sf];
        hB_hi[0][frag_off(sm, H1 + sf)] = (short)f2bf(v);
        xv = x[((size_t)(b0 + sm) * Tz + t0 + tstep) * Fz + sf];
    }
    // strided pointers (advance by tstep*stride per step)
    const float* xp = x + ((size_t)(b0 + sm) * Tz + t0 + 2 * tstep) * Fz + sf;
    const ptrdiff_t xinc = (ptrdiff_t)tstep * Fz;
    unsigned short* yp = y1 + (((size_t)t0 * 128 + tb) * 140 + dir * H1) * 16 + n;
    const ptrdiff_t yinc = (ptrdiff_t)tstep * (140 * 128 * 16);

    // hoisted LDS write offsets (loop-invariant)
    const int xoff = frag_off(sm, H1 + sf);
    int hoff[3];
#pragma unroll
    for (int tt = 0; tt < 3; ++tt) hoff[tt] = frag_off(n, 4 * (wv + 6 * tt) + quad);

    float cst[3];
    cst[0] = 0.0f; cst[1] = 0.0f; cst[2] = 0.0f;

    // one step; pp is a literal at each call site -> all LDS addrs invariant
    auto body = [&](int step, const int pp) __attribute__((always_inline)) {
        sync_lds();   // buf[pp] complete, buf[pp^1] free (LDS-only barrier)

        if (stg && step + 1 < Tz) {
            hB_hi[pp ^ 1][xoff] = (short)f2bf(xv);
        }
        if (stg && step + 2 < Tz) {
            xv = *xp;
        }

        short8 bhi[3];
#pragma unroll
        for (int q = 0; q < 3; ++q)
            bhi[q] = *(const short8*)&hB_hi[pp][q * 512 + lane * 8];

        float4v accA[3], accB[3];
#pragma unroll
        for (int tt = 0; tt < 3; ++tt) {
            accA[tt] = (float4v){0.f, 0.f, 0.f, 0.f};
            accB[tt] = (float4v){0.f, 0.f, 0.f, 0.f};
        }
#pragma unroll
        for (int tt = 0; tt < 3; ++tt) {
            accA[tt] = MFMA16(whi[tt][0], bhi[0], accA[tt]);
            accB[tt] = MFMA16(wlo[tt][0], bhi[0], accB[tt]);
            accA[tt] = MFMA16(whi[tt][1], bhi[1], accA[tt]);
            accB[tt] = MFMA16(wlo[tt][1], bhi[1], accB[tt]);
            accA[tt] = MFMA16(whi[tt][2], bhi[2], accA[tt]);
            accB[tt] = MFMA16(wlo[tt][2], bhi[2], accB[tt]);
        }

#pragma unroll
        for (int tt = 0; tt < 3; ++tt) {
            const int u = 4 * (wv + 6 * tt) + quad;
            if (u < H1) {
                float gi = accA[tt][0] + accB[tt][0];
                float gf = accA[tt][1] + accB[tt][1];
                float gc = accA[tt][2] + accB[tt][2];
                float go = accA[tt][3] + accB[tt][3];
                float cn = sigf(gf) * cst[tt] + sigf(gi) * tanhfast(gc);
                float h  = sigf(go) * tanhfast(cn);
                cst[tt] = cn;
                unsigned short hh = f2bf(h);
                hB_hi[pp ^ 1][hoff[tt]] = (short)hh;
                yp[u * 16] = hh;
            }
        }
        xp += xinc;
        yp += yinc;
    };

    for (int step = 0; step < Tz; step += 2) {
        body(step, 0);
        body(step + 1, 1);
    }
}

// ---------------------------------------------------------------------------
// Layer 2 (MFMA, D = W x h): input 140 (bf16 y1 [T][128][140][16]), hidden 21.
// [round-13 structure: 6 balanced waves] Grid 256 = 2 dir x 128 tiles of 16
// rows. 384 thr = 6 waves; wave w computes tile w (u = 4w+quad, u<21); x
// staging (280 x 16B vector loads) spread evenly over waves 0..4 (es = tid).
// K: 0..20 = h, 21 = bias, 32..171 = x. h/x hi-only; W-lo for chunk 0 only:
// 7 MFMA/wave. LDS-only barrier, dbuf, prefetch depth 2, x2 unroll.
// ---------------------------------------------------------------------------
__global__ __launch_bounds__(384, 2) void k_lstm2(
    const unsigned short* __restrict__ y1,
    const float* __restrict__ wih_f, const float* __restrict__ whh_f,
    const float* __restrict__ bih_f, const float* __restrict__ bhh_f,
    const float* __restrict__ wih_b, const float* __restrict__ whh_b,
    const float* __restrict__ bih_b, const float* __restrict__ bhh_b,
    unsigned short* __restrict__ y2)   // [B][T][42] bf16
{
    __shared__ short hB_hi[2][3072];   // 192 k x 16 batch

    const int tb  = blockIdx.x & 127;
    const int dir = blockIdx.x >> 7;
    const int b0  = tb << 4;
    const float* wih = dir ? wih_b : wih_f;
    const float* whh = dir ? whh_b : whh_f;
    const float* bih = dir ? bih_b : bih_f;
    const float* bhh = dir ? bhh_b : bhh_f;

    const int tid  = threadIdx.x;
    const int wv   = tid >> 6;          // 0..5 — all waves compute
    const int lane = tid & 63;
    const int n    = lane & 15;
    const int quad = lane >> 4;

    // ---- W-side preload: hi all chunks, lo chunk 0 ----
    short8 whi[6], wlo0;
    const int g_ = n & 3;
    {
        const int uu = 4 * wv + (n >> 2);
#pragma unroll
        for (int q = 0; q < 6; ++q) {
#pragma unroll
            for (int j = 0; j < 8; ++j) {
                int k = q * 32 + quad * 8 + j;
                float v = 0.0f;
                if (uu < H2) {
                    int row = g_ * H2 + uu;
                    if (k < H2)                   v = whh[row * H2 + k];
                    else if (k == 21)             v = bih[row] + bhh[row];
                    else if (k >= 32 && k < 172)  v = wih[row * 140 + (k - 32)];
                }
                unsigned short hi = f2bf(v);
                whi[q][j] = (short)hi;
                if (q == 0) wlo0[j] = (short)f2bf(v - bf2f(hi));
            }
        }
    }

    // ---- init LDS ----
    for (int e = tid; e < 3072; e += 384) { hB_hi[0][e] = 0; hB_hi[1][e] = 0; }
    __syncthreads();
    if (tid < 16) {
        int off = frag_off(tid, 21);
        hB_hi[0][off] = (short)0x3F80;   // bias const 1.0
        hB_hi[1][off] = (short)0x3F80;
    }

    // ---- stagers: es in [0,280); each loads 16B (8 ushorts); waves 0..4 ----
    const int es = tid;
    const bool stg = (es < 280);

    const int tstep = dir ? -1 : 1;
    const int t0    = dir ? (Tz - 1) : 0;

    // prologue: stage x(t0) into buf 0; preload x(t1)
    short8 xr = (short8){0,0,0,0,0,0,0,0};
    if (stg) {
        short8 v = *(const short8*)(y1 + ((size_t)t0 * 128 + tb) * 2240 + es * 8);
#pragma unroll
        for (int j = 0; j < 8; ++j) {
            int idx = es * 8 + j;
            hB_hi[0][frag_off(idx & 15, 32 + (idx >> 4))] = v[j];
        }
        xr = *(const short8*)(y1 + ((size_t)(t0 + tstep) * 128 + tb) * 2240 + es * 8);
    }
    // strided pointers
    const unsigned short* srcp =
        y1 + ((size_t)(t0 + 2 * tstep) * 128 + tb) * 2240 + es * 8;
    const ptrdiff_t sinc = (ptrdiff_t)tstep * (128 * 2240);
    unsigned short* yp2 = y2 + ((size_t)(b0 + n) * Tz + t0) * 42 + dir * H2;
    const ptrdiff_t yinc = (ptrdiff_t)tstep * 42;

    // hoisted LDS offsets
    int xoffs[8];
#pragma unroll
    for (int j = 0; j < 8; ++j) {
        int idx = es * 8 + j;
        xoffs[j] = frag_off(idx & 15, 32 + (idx >> 4));
    }
    const int u     = 4 * wv + quad;
    const int hoffc = frag_off(n, (u < H2) ? u : 0);

    float cst = 0.0f;

    auto body = [&](int step, const int pp) __attribute__((always_inline)) {
        sync_lds();   // LDS-only barrier

        if (stg && step + 1 < Tz) {
#pragma unroll
            for (int j = 0; j < 8; ++j)
                hB_hi[pp ^ 1][xoffs[j]] = xr[j];
        }
        if (stg && step + 2 < Tz) {
            xr = *(const short8*)srcp;
        }

        short8 bhi[6];
#pragma unroll
        for (int q = 0; q < 6; ++q)
            bhi[q] = *(const short8*)&hB_hi[pp][q * 512 + lane * 8];

        float4v accA = (float4v){0.f, 0.f, 0.f, 0.f};
        float4v accB = (float4v){0.f, 0.f, 0.f, 0.f};
        accA = MFMA16(whi[0], bhi[0], accA);
        accB = MFMA16(wlo0,   bhi[0], accB);
        accA = MFMA16(whi[2], bhi[2], accA);
        accB = MFMA16(whi[1], bhi[1], accB);
        accA = MFMA16(whi[4], bhi[4], accA);
        accB = MFMA16(whi[3], bhi[3], accB);
        accB = MFMA16(whi[5], bhi[5], accB);

        if (u < H2) {
            float gi = accA[0] + accB[0];
            float gf = accA[1] + accB[1];
            float gc = accA[2] + accB[2];
            float go = accA[3] + accB[3];
            float cn = sigf(gf) * cst + sigf(gi) * tanhfast(gc);
            float h  = sigf(go) * tanhfast(cn);
            cst = cn;
            unsigned short hh = f2bf(h);
            hB_hi[pp ^ 1][hoffc] = (short)hh;
            yp2[u] = hh;
        }
        srcp += sinc;
        yp2  += yinc;
    };

    for (int step = 0; step < Tz; step += 2) {
        body(step, 0);
        body(step + 1, 1);
    }
}

// ---------------------------------------------------------------------------
// Dense head: thread per (b,t). Weights via uniform scalar loads.
// ---------------------------------------------------------------------------
__global__ __launch_bounds__(256) void k_dense(
    const unsigned short* __restrict__ y2,
    const float* __restrict__ wd1, const float* __restrict__ bd1,
    const float* __restrict__ wd2, const float* __restrict__ bd2,
    const float* __restrict__ wo,  const float* __restrict__ bo,
    float* __restrict__ out)
{
    int idx = blockIdx.x * 256 + threadIdx.x;
    if (idx >= Bz * Tz) return;
    const unsigned int* row = (const unsigned int*)&y2[(size_t)idx * 42];

    float v[42];
#pragma unroll
    for (int j = 0; j < 21; ++j) {
        unsigned int p = row[j];
        v[2 * j]     = bf2f((unsigned short)(p & 0xFFFFu));
        v[2 * j + 1] = bf2f((unsigned short)(p >> 16));
    }

    float h1[30];
#pragma unroll
    for (int o = 0; o < 30; ++o) {
        float s = bd1[o];
#pragma unroll
        for (int j = 0; j < 42; ++j) s = fmaf(v[j], wd1[o * 42 + j], s);
        h1[o] = fmaxf(s, 0.0f);
    }
    float outv = bo[0];
#pragma unroll
    for (int o = 0; o < 20; ++o) {
        float s = bd2[o];
#pragma unroll
        for (int j = 0; j < 30; ++j) s = fmaf(h1[j], wd2[o * 30 + j], s);
        outv = fmaf(fmaxf(s, 0.0f), wo[o], outv);
    }
    out[idx] = outv;
}

// ---------------------------------------------------------------------------
extern "C" void kernel_launch(void* const* d_in, const int* in_sizes, int n_in,
                              void* d_out, int out_size, void* d_ws, size_t ws_size,
                              hipStream_t stream)
{
    const float* x      = (const float*)d_in[0];
    const float* w1f_ih = (const float*)d_in[1];
    const float* w1f_hh = (const float*)d_in[2];
    const float* b1f_ih = (const float*)d_in[3];
    const float* b1f_hh = (const float*)d_in[4];
    const float* w1b_ih = (const float*)d_in[5];
    const float* w1b_hh = (const float*)d_in[6];
    const float* b1b_ih = (const float*)d_in[7];
    const float* b1b_hh = (const float*)d_in[8];
    const float* w2f_ih = (const float*)d_in[9];
    const float* w2f_hh = (const float*)d_in[10];
    const float* b2f_ih = (const float*)d_in[11];
    const float* b2f_hh = (const float*)d_in[12];
    const float* w2b_ih = (const float*)d_in[13];
    const float* w2b_hh = (const float*)d_in[14];
    const float* b2b_ih = (const float*)d_in[15];
    const float* b2b_hh = (const float*)d_in[16];
    const float* wd1    = (const float*)d_in[17];
    const float* bd1    = (const float*)d_in[18];
    const float* wd2    = (const float*)d_in[19];
    const float* bd2    = (const float*)d_in[20];
    const float* wo     = (const float*)d_in[21];
    const float* bo     = (const float*)d_in[22];
    float* out = (float*)d_out;

    // Workspace: y1 bf16 [T][128][140][16] (192.7 MB) + y2 bf16 [B][T][42] (57.8 MB)
    const size_t y1_elems = (size_t)Tz * 128 * 2240;
    const size_t y2_elems = (size_t)Bz * Tz * 42;
    if (ws_size < (y1_elems + y2_elems) * 2) return;

    unsigned short* y1 = (unsigned short*)d_ws;
    unsigned short* y2 = y1 + y1_elems;

    hipLaunchKernelGGL(k_lstm1, dim3(256), dim3(384), 0, stream,
                       x, w1f_ih, w1f_hh, b1f_ih, b1f_hh,
                       w1b_ih, w1b_hh, b1b_ih, b1b_hh, y1);
    hipLaunchKernelGGL(k_lstm2, dim3(256), dim3(384), 0, stream,
                       y1, w2f_ih, w2f_hh, b2f_ih, b2f_hh,
                       w2b_ih, w2b_hh, b2b_ih, b2b_hh, y2);
    hipLaunchKernelGGL(k_dense, dim3((Bz * Tz + 255) / 256), dim3(256), 0, stream,
                       y2, wd1, bd1, wd2, bd2, wo, bo, out);
}

// Round 11
// 720.666 us; speedup vs baseline: 2.6353x; 1.1217x over previous
//
#include <hip/hip_runtime.h>

// Problem constants
#define Bz 2048
#define Tz 336
#define Fz 10
#define H1 70
#define H2 21

typedef __attribute__((ext_vector_type(8))) short short8;   // 8 bf16 = 4 VGPR
typedef __attribute__((ext_vector_type(4))) float float4v;  // MFMA acc

#define MFMA16(a, b, c) __builtin_amdgcn_mfma_f32_16x16x32_bf16((a), (b), (c), 0, 0, 0)

// LDS-only barrier (composable-kernel idiom): orders LDS across the block
// WITHOUT draining vmcnt — __syncthreads() would stall on the y1/y2 global
// stores (never read in-kernel) every step (~200-900 cyc store-ack, m126).
__device__ __forceinline__ void sync_lds() {
    asm volatile("s_waitcnt lgkmcnt(0)\n\ts_barrier" ::: "memory");
}

__device__ __forceinline__ float sigf(float x) {
    return 1.0f / (1.0f + __expf(-x));
}
__device__ __forceinline__ float tanhfast(float x) {
    float t = __expf(2.0f * x);
    return 1.0f - 2.0f / (t + 1.0f);
}
__device__ __forceinline__ unsigned short f2bf(float v) {
    unsigned int u = __float_as_uint(v);
    u += 0x7FFFu + ((u >> 16) & 1u);
    return (unsigned short)(u >> 16);
}
__device__ __forceinline__ float bf2f(unsigned short s) {
    return __uint_as_float(((unsigned int)s) << 16);
}

// Fragment-order LDS offset (in shorts) for (col m, k):
// (m, k) lives at ((k>>3)*16 + m)*8 + (k&7)
__device__ __forceinline__ int frag_off(int m, int k) {
    return (k >> 3) * 128 + m * 8 + (k & 7);
}

// ---------------------------------------------------------------------------
// Layer 1 (MFMA, D = W x h): input F=10, hidden 70.
// [round-14: 12 waves, max-2-tiles, role-separated, SIMD-balanced]
// Measured: r0 (16w, max2, stagers stacked) 2963 cyc/step; r9 (6w, 3 tiles)
// 3476 cyc/step -> 3rd serial tile costs ~500 cyc (exposed chain latency),
// and 6 waves on 4 SIMDs is unbalanced. This round keeps max 2 tiles/wave,
// balances SIMDs (12 waves = exactly 3/SIMD), splits the straggler role over
// 6 waves instead of 2, and moves staging to single-tile waves 9-10.
// Tiles: waves 0-5 own {wv, wv+6}; waves 6-11 own {wv+6} (12..17). 18 total.
//   K: 0..69 = h, 70..79 = x, 80 = bias slot (B col 1.0), 81..95 = 0.
// h bf16 hi-only in LDS; W hi+lo in registers (6 MFMA/tile). ONE LDS-only
// barrier per step, double-buffered B-LDS, x prefetch depth 2, step loop
// unrolled x2 (pp literal), strided pointers. Arithmetic identical to the
// 719us baseline (absmax parity). y1 layout: [T][128][140][16] bf16.
// launch_bounds(768,3): 12-wave block needs 3 waves/SIMD -> VGPR <= 170.
// ---------------------------------------------------------------------------
__global__ __launch_bounds__(768, 3) void k_lstm1(
    const float* __restrict__ x,
    const float* __restrict__ wih_f, const float* __restrict__ whh_f,
    const float* __restrict__ bih_f, const float* __restrict__ bhh_f,
    const float* __restrict__ wih_b, const float* __restrict__ whh_b,
    const float* __restrict__ bih_b, const float* __restrict__ bhh_b,
    unsigned short* __restrict__ y1)
{
    __shared__ short hB_hi[2][1536];   // 96 k x 16 batch, frag order, dbuf

    const int tb  = blockIdx.x & 127;
    const int dir = blockIdx.x >> 7;
    const int b0  = tb << 4;
    const float* wih = dir ? wih_b : wih_f;
    const float* whh = dir ? whh_b : whh_f;
    const float* bih = dir ? bih_b : bih_f;
    const float* bhh = dir ? bhh_b : bhh_f;

    const int tid  = threadIdx.x;
    const int wv   = tid >> 6;          // 0..11
    const int lane = tid & 63;
    const int n    = lane & 15;
    const int quad = lane >> 4;
    const int NT1  = (wv < 6) ? 2 : 1;  // tiles this wave owns
    int ptile[2];
    ptile[0] = (wv < 6) ? wv : (wv + 6);   // waves 6-11 -> tiles 12..17
    ptile[1] = wv + 6;                     // waves 0-5  -> tiles 6..11

    // ---- W-side (A-operand) preload, hi+lo bf16 ----
    short8 whi[2][3], wlo[2][3];
    const int g_ = n & 3;
#pragma unroll
    for (int tt = 0; tt < 2; ++tt) {
        if (tt < NT1) {
            const int p  = ptile[tt];
            const int uu = 4 * p + (n >> 2);
#pragma unroll
            for (int q = 0; q < 3; ++q) {
#pragma unroll
                for (int j = 0; j < 8; ++j) {
                    int k = q * 32 + quad * 8 + j;
                    float v = 0.0f;
                    if (uu < H1) {
                        int row = g_ * H1 + uu;
                        if (k < H1)        v = whh[row * H1 + k];
                        else if (k < 80)   v = wih[row * Fz + (k - H1)];
                        else if (k == 80)  v = bih[row] + bhh[row];
                    }
                    unsigned short hi = f2bf(v);
                    unsigned short lo = f2bf(v - bf2f(hi));
                    whi[tt][q][j] = (short)hi;
                    wlo[tt][q][j] = (short)lo;
                }
            }
        }
    }

    // ---- init LDS ----
    for (int e = tid; e < 1536; e += 768) {
        hB_hi[0][e] = 0; hB_hi[1][e] = 0;
    }
    __syncthreads();
    if (tid < 16) {
        int off = 1280 + tid * 8;       // frag_off(tid, 80)
        hB_hi[0][off] = (short)0x3F80;  // bf16(1.0) bias const
        hB_hi[1][off] = (short)0x3F80;
    }

    // ---- stagers: es in [0,160) -> (m, f), threads 576..735 (waves 9-10) ----
    const int es = tid - 576;
    const bool stg = (es >= 0 && es < 160);
    int sm = 0, sf = 0;
    if (stg) { sm = es / Fz; sf = es % Fz; }

    const int tstep = dir ? -1 : 1;
    const int t0    = dir ? (Tz - 1) : 0;

    // prologue: stage x(t0) into buf 0; preload x(t1) into regs
    float xv = 0.0f;
    if (stg) {
        float v = x[((size_t)(b0 + sm) * Tz + t0) * Fz + sf];
        hB_hi[0][frag_off(sm, H1 + sf)] = (short)f2bf(v);
        xv = x[((size_t)(b0 + sm) * Tz + t0 + tstep) * Fz + sf];
    }
    // strided pointers (advance by tstep*stride per step)
    const float* xp = x + ((size_t)(b0 + sm) * Tz + t0 + 2 * tstep) * Fz + sf;
    const ptrdiff_t xinc = (ptrdiff_t)tstep * Fz;
    unsigned short* yp = y1 + (((size_t)t0 * 128 + tb) * 140 + dir * H1) * 16 + n;
    const ptrdiff_t yinc = (ptrdiff_t)tstep * (140 * 128 * 16);

    // hoisted LDS write offsets (loop-invariant)
    const int xoff = frag_off(sm, H1 + sf);
    int hoff[2];
#pragma unroll
    for (int tt = 0; tt < 2; ++tt) hoff[tt] = frag_off(n, 4 * ptile[tt] + quad);

    float cst[2];
    cst[0] = 0.0f; cst[1] = 0.0f;

    // one step; pp is a literal at each call site -> all LDS addrs invariant
    auto body = [&](int step, const int pp) __attribute__((always_inline)) {
        sync_lds();   // buf[pp] complete, buf[pp^1] free (LDS-only barrier)

        if (stg && step + 1 < Tz) {
            hB_hi[pp ^ 1][xoff] = (short)f2bf(xv);
        }
        if (stg && step + 2 < Tz) {
            xv = *xp;
        }

        short8 bhi[3];
#pragma unroll
        for (int q = 0; q < 3; ++q)
            bhi[q] = *(const short8*)&hB_hi[pp][q * 512 + lane * 8];

        float4v accA[2], accB[2];
#pragma unroll
        for (int tt = 0; tt < 2; ++tt) {
            accA[tt] = (float4v){0.f, 0.f, 0.f, 0.f};
            accB[tt] = (float4v){0.f, 0.f, 0.f, 0.f};
        }
#pragma unroll
        for (int tt = 0; tt < 2; ++tt) {
            if (tt < NT1) {
                accA[tt] = MFMA16(whi[tt][0], bhi[0], accA[tt]);
                accB[tt] = MFMA16(wlo[tt][0], bhi[0], accB[tt]);
                accA[tt] = MFMA16(whi[tt][1], bhi[1], accA[tt]);
                accB[tt] = MFMA16(wlo[tt][1], bhi[1], accB[tt]);
                accA[tt] = MFMA16(whi[tt][2], bhi[2], accA[tt]);
                accB[tt] = MFMA16(wlo[tt][2], bhi[2], accB[tt]);
            }
        }

#pragma unroll
        for (int tt = 0; tt < 2; ++tt) {
            if (tt < NT1) {
                const int u = 4 * ptile[tt] + quad;
                if (u < H1) {
                    float gi = accA[tt][0] + accB[tt][0];
                    float gf = accA[tt][1] + accB[tt][1];
                    float gc = accA[tt][2] + accB[tt][2];
                    float go = accA[tt][3] + accB[tt][3];
                    float cn = sigf(gf) * cst[tt] + sigf(gi) * tanhfast(gc);
                    float h  = sigf(go) * tanhfast(cn);
                    cst[tt] = cn;
                    unsigned short hh = f2bf(h);
                    hB_hi[pp ^ 1][hoff[tt]] = (short)hh;
                    yp[u * 16] = hh;
                }
            }
        }
        xp += xinc;
        yp += yinc;
    };

    for (int step = 0; step < Tz; step += 2) {
        body(step, 0);
        body(step + 1, 1);
    }
}

// ---------------------------------------------------------------------------
// Layer 2 (MFMA, D = W x h): input 140 (bf16 y1 [T][128][140][16]), hidden 21.
// [round-14: 12 waves, role-separated] Grid 256 = 2 dir x 128 tiles of 16
// rows. 768 thr = 12 waves: waves 0..5 PURE compute (tile wv, u = 4wv+quad,
// u<21; zero staging on compute waves); waves 6..10 stage x (threads
// 384..663, 280 x 16B vector loads, 1 each). K: 0..20 = h, 21 = bias,
// 32..171 = x. h/x hi-only; W-lo chunk 0 only: 7 MFMA/wave. LDS-only
// barrier, dbuf, prefetch depth 2, x2 unroll. Arithmetic identical to the
// 719us baseline.
// ---------------------------------------------------------------------------
__global__ __launch_bounds__(768, 3) void k_lstm2(
    const unsigned short* __restrict__ y1,
    const float* __restrict__ wih_f, const float* __restrict__ whh_f,
    const float* __restrict__ bih_f, const float* __restrict__ bhh_f,
    const float* __restrict__ wih_b, const float* __restrict__ whh_b,
    const float* __restrict__ bih_b, const float* __restrict__ bhh_b,
    unsigned short* __restrict__ y2)   // [B][T][42] bf16
{
    __shared__ short hB_hi[2][3072];   // 192 k x 16 batch

    const int tb  = blockIdx.x & 127;
    const int dir = blockIdx.x >> 7;
    const int b0  = tb << 4;
    const float* wih = dir ? wih_b : wih_f;
    const float* whh = dir ? whh_b : whh_f;
    const float* bih = dir ? bih_b : bih_f;
    const float* bhh = dir ? bhh_b : bhh_f;

    const int tid  = threadIdx.x;
    const int wv   = tid >> 6;          // 0..11
    const int lane = tid & 63;
    const int n    = lane & 15;
    const int quad = lane >> 4;
    const bool comp = (wv < 6);

    // ---- W-side preload (waves 0..5): hi all chunks, lo chunk 0 ----
    short8 whi[6], wlo0;
    const int g_ = n & 3;
    if (comp) {
        const int uu = 4 * wv + (n >> 2);
#pragma unroll
        for (int q = 0; q < 6; ++q) {
#pragma unroll
            for (int j = 0; j < 8; ++j) {
                int k = q * 32 + quad * 8 + j;
                float v = 0.0f;
                if (uu < H2) {
                    int row = g_ * H2 + uu;
                    if (k < H2)                   v = whh[row * H2 + k];
                    else if (k == 21)             v = bih[row] + bhh[row];
                    else if (k >= 32 && k < 172)  v = wih[row * 140 + (k - 32)];
                }
                unsigned short hi = f2bf(v);
                whi[q][j] = (short)hi;
                if (q == 0) wlo0[j] = (short)f2bf(v - bf2f(hi));
            }
        }
    }

    // ---- init LDS ----
    for (int e = tid; e < 3072; e += 768) { hB_hi[0][e] = 0; hB_hi[1][e] = 0; }
    __syncthreads();
    if (tid < 16) {
        int off = frag_off(tid, 21);
        hB_hi[0][off] = (short)0x3F80;   // bias const 1.0
        hB_hi[1][off] = (short)0x3F80;
    }

    // ---- stagers: es in [0,280); threads 384..663 (waves 6-10), 16B each ----
    const int es = tid - 384;
    const bool stg = (es >= 0 && es < 280);

    const int tstep = dir ? -1 : 1;
    const int t0    = dir ? (Tz - 1) : 0;

    // prologue: stage x(t0) into buf 0; preload x(t1)
    short8 xr = (short8){0,0,0,0,0,0,0,0};
    if (stg) {
        short8 v = *(const short8*)(y1 + ((size_t)t0 * 128 + tb) * 2240 + es * 8);
#pragma unroll
        for (int j = 0; j < 8; ++j) {
            int idx = es * 8 + j;
            hB_hi[0][frag_off(idx & 15, 32 + (idx >> 4))] = v[j];
        }
        xr = *(const short8*)(y1 + ((size_t)(t0 + tstep) * 128 + tb) * 2240 + es * 8);
    }
    // strided pointers
    const unsigned short* srcp =
        y1 + ((size_t)(t0 + 2 * tstep) * 128 + tb) * 2240 + es * 8;
    const ptrdiff_t sinc = (ptrdiff_t)tstep * (128 * 2240);
    unsigned short* yp2 = y2 + ((size_t)(b0 + n) * Tz + t0) * 42 + dir * H2;
    const ptrdiff_t yinc = (ptrdiff_t)tstep * 42;

    // hoisted LDS offsets
    int xoffs[8];
#pragma unroll
    for (int j = 0; j < 8; ++j) {
        int idx = es * 8 + j;
        xoffs[j] = frag_off(idx & 15, 32 + (idx >> 4));
    }
    const int u     = 4 * wv + quad;
    const int hoffc = frag_off(n, (u < H2) ? u : 0);

    float cst = 0.0f;

    auto body = [&](int step, const int pp) __attribute__((always_inline)) {
        sync_lds();   // LDS-only barrier

        if (stg && step + 1 < Tz) {
#pragma unroll
            for (int j = 0; j < 8; ++j)
                hB_hi[pp ^ 1][xoffs[j]] = xr[j];
        }
        if (stg && step + 2 < Tz) {
            xr = *(const short8*)srcp;
        }

        if (comp) {
            short8 bhi[6];
#pragma unroll
            for (int q = 0; q < 6; ++q)
                bhi[q] = *(const short8*)&hB_hi[pp][q * 512 + lane * 8];

            float4v accA = (float4v){0.f, 0.f, 0.f, 0.f};
            float4v accB = (float4v){0.f, 0.f, 0.f, 0.f};
            accA = MFMA16(whi[0], bhi[0], accA);
            accB = MFMA16(wlo0,   bhi[0], accB);
            accA = MFMA16(whi[2], bhi[2], accA);
            accB = MFMA16(whi[1], bhi[1], accB);
            accA = MFMA16(whi[4], bhi[4], accA);
            accB = MFMA16(whi[3], bhi[3], accB);
            accB = MFMA16(whi[5], bhi[5], accB);

            if (u < H2) {
                float gi = accA[0] + accB[0];
                float gf = accA[1] + accB[1];
                float gc = accA[2] + accB[2];
                float go = accA[3] + accB[3];
                float cn = sigf(gf) * cst + sigf(gi) * tanhfast(gc);
                float h  = sigf(go) * tanhfast(cn);
                cst = cn;
                unsigned short hh = f2bf(h);
                hB_hi[pp ^ 1][hoffc] = (short)hh;
                yp2[u] = hh;
            }
        }
        srcp += sinc;
        yp2  += yinc;
    };

    for (int step = 0; step < Tz; step += 2) {
        body(step, 0);
        body(step + 1, 1);
    }
}

// ---------------------------------------------------------------------------
// Dense head: thread per (b,t). Weights via uniform scalar loads.
// ---------------------------------------------------------------------------
__global__ __launch_bounds__(256) void k_dense(
    const unsigned short* __restrict__ y2,
    const float* __restrict__ wd1, const float* __restrict__ bd1,
    const float* __restrict__ wd2, const float* __restrict__ bd2,
    const float* __restrict__ wo,  const float* __restrict__ bo,
    float* __restrict__ out)
{
    int idx = blockIdx.x * 256 + threadIdx.x;
    if (idx >= Bz * Tz) return;
    const unsigned int* row = (const unsigned int*)&y2[(size_t)idx * 42];

    float v[42];
#pragma unroll
    for (int j = 0; j < 21; ++j) {
        unsigned int p = row[j];
        v[2 * j]     = bf2f((unsigned short)(p & 0xFFFFu));
        v[2 * j + 1] = bf2f((unsigned short)(p >> 16));
    }

    float h1[30];
#pragma unroll
    for (int o = 0; o < 30; ++o) {
        float s = bd1[o];
#pragma unroll
        for (int j = 0; j < 42; ++j) s = fmaf(v[j], wd1[o * 42 + j], s);
        h1[o] = fmaxf(s, 0.0f);
    }
    float outv = bo[0];
#pragma unroll
    for (int o = 0; o < 20; ++o) {
        float s = bd2[o];
#pragma unroll
        for (int j = 0; j < 30; ++j) s = fmaf(h1[j], wd2[o * 30 + j], s);
        outv = fmaf(fmaxf(s, 0.0f), wo[o], outv);
    }
    out[idx] = outv;
}

// ---------------------------------------------------------------------------
extern "C" void kernel_launch(void* const* d_in, const int* in_sizes, int n_in,
                              void* d_out, int out_size, void* d_ws, size_t ws_size,
                              hipStream_t stream)
{
    const float* x      = (const float*)d_in[0];
    const float* w1f_ih = (const float*)d_in[1];
    const float* w1f_hh = (const float*)d_in[2];
    const float* b1f_ih = (const float*)d_in[3];
    const float* b1f_hh = (const float*)d_in[4];
    const float* w1b_ih = (const float*)d_in[5];
    const float* w1b_hh = (const float*)d_in[6];
    const float* b1b_ih = (const float*)d_in[7];
    const float* b1b_hh = (const float*)d_in[8];
    const float* w2f_ih = (const float*)d_in[9];
    const float* w2f_hh = (const float*)d_in[10];
    const float* b2f_ih = (const float*)d_in[11];
    const float* b2f_hh = (const float*)d_in[12];
    const float* w2b_ih = (const float*)d_in[13];
    const float* w2b_hh = (const float*)d_in[14];
    const float* b2b_ih = (const float*)d_in[15];
    const float* b2b_hh = (const float*)d_in[16];
    const float* wd1    = (const float*)d_in[17];
    const float* bd1    = (const float*)d_in[18];
    const float* wd2    = (const float*)d_in[19];
    const float* bd2    = (const float*)d_in[20];
    const float* wo     = (const float*)d_in[21];
    const float* bo     = (const float*)d_in[22];
    float* out = (float*)d_out;

    // Workspace: y1 bf16 [T][128][140][16] (192.7 MB) + y2 bf16 [B][T][42] (57.8 MB)
    const size_t y1_elems = (size_t)Tz * 128 * 2240;
    const size_t y2_elems = (size_t)Bz * Tz * 42;
    if (ws_size < (y1_elems + y2_elems) * 2) return;

    unsigned short* y1 = (unsigned short*)d_ws;
    unsigned short* y2 = y1 + y1_elems;

    hipLaunchKernelGGL(k_lstm1, dim3(256), dim3(768), 0, stream,
                       x, w1f_ih, w1f_hh, b1f_ih, b1f_hh,
                       w1b_ih, w1b_hh, b1b_ih, b1b_hh, y1);
    hipLaunchKernelGGL(k_lstm2, dim3(256), dim3(768), 0, stream,
                       y1, w2f_ih, w2f_hh, b2f_ih, b2f_hh,
                       w2b_ih, w2b_hh, b2b_ih, b2b_hh, y2);
    hipLaunchKernelGGL(k_dense, dim3((Bz * Tz + 255) / 256), dim3(256), 0, stream,
                       y2, wd1, bd1, wd2, bd2, wo, bo, out);
}

// Round 12
// 582.101 us; speedup vs baseline: 3.2626x; 1.2380x over previous
//
#include <hip/hip_runtime.h>

// Problem constants
#define Bz 2048
#define Tz 336
#define Fz 10
#define H1 70
#define H2 21

typedef __attribute__((ext_vector_type(8))) short short8;   // 8 bf16 = 4 VGPR
typedef __attribute__((ext_vector_type(4))) float float4v;  // MFMA acc

#define MFMA16(a, b, c) __builtin_amdgcn_mfma_f32_16x16x32_bf16((a), (b), (c), 0, 0, 0)

// LDS-only barrier (composable-kernel idiom): orders LDS across the block
// WITHOUT draining vmcnt — __syncthreads() would stall on the y1/y2 global
// stores (never read in-kernel) every step (~200-900 cyc store-ack, m126).
__device__ __forceinline__ void sync_lds() {
    asm volatile("s_waitcnt lgkmcnt(0)\n\ts_barrier" ::: "memory");
}

__device__ __forceinline__ unsigned short f2bf(float v) {
    unsigned int u = __float_as_uint(v);
    u += 0x7FFFu + ((u >> 16) & 1u);
    return (unsigned short)(u >> 16);
}
__device__ __forceinline__ float bf2f(unsigned short s) {
    return __uint_as_float(((unsigned int)s) << 16);
}

// [round-12 diet] LSTM gate epilogue with common-denominator algebra:
//   cn = sig(f)*c + sig(i)*tanh(g);  h = sig(o)*tanh(cn)
// via a=e^-f, b=e^-i, d=e^2g:  cn = (c*pb*pd + pa*(d-1)) / (pa*pb*pd)
// 5 exp + 2 divisions (vs 5 exp + 5 divisions in the sigf/tanhfast form).
// Same exponentials, association-level difference only. Kernel is
// VALU-ISSUE-bound (r11: VALUBusy 69.5% x 3070cyc = 2130 issue-cyc/SIMD/step)
// so refined-division sequences (~7 instr each) are the dominant cost.
// Overflow-safe for this weight init: |gate| <~ 35 << 88.
__device__ __forceinline__ float lstm_gate_h(float gi, float gf, float gc,
                                             float go, float& cst) {
    float a  = __expf(-gf);
    float b  = __expf(-gi);
    float d  = __expf(2.0f * gc);
    float pa = 1.0f + a;
    float pb = 1.0f + b;
    float pd = d + 1.0f;
    float t1 = pb * pd;
    float num = fmaf(pa, d - 1.0f, cst * t1);
    float cn  = num / (pa * t1);
    float e2  = __expf(-go);
    float f2  = __expf(2.0f * cn);
    float h   = (f2 - 1.0f) / ((1.0f + e2) * (f2 + 1.0f));
    cst = cn;
    return h;
}

// Fragment-order LDS offset (in shorts) for (col m, k):
// (m, k) lives at ((k>>3)*16 + m)*8 + (k&7)
__device__ __forceinline__ int frag_off(int m, int k) {
    return (k >> 3) * 128 + m * 8 + (k & 7);
}

// ---------------------------------------------------------------------------
// Layer 1 (MFMA, D = W x h): input F=10, hidden 70.  [r0 structure + diet]
// Topology result (r0/r9/r11): step time invariant to wave count (2963/3476/
// 3070 cyc) -> issue-bound, so keep the best-measured r0 16-wave structure
// and cut VALU issue: merged hi/lo MFMA chain (single acc: -4 movs -4 adds
// per tile) + common-denominator gate math (5 -> 2 divisions per tile).
// Grid 256 = 2 dir x 128 tiles of 16 batch rows. 1024 threads = 16 waves.
// 18 M-tiles: wave w owns tile w; waves 0,1 also own tiles 16,17.
//   K: 0..69 = h, 70..79 = x, 80 = bias slot (B col 1.0), 81..95 = 0.
// h bf16 hi-only in LDS; W hi+lo in registers (6 MFMA/tile). ONE LDS-only
// barrier per step (sync_lds), double-buffered B-LDS, x prefetch depth 2,
// step loop unrolled x2 (pp literal), strided pointers.
// y1 layout: [T][128][140][16] bf16.
// ---------------------------------------------------------------------------
__global__ __launch_bounds__(1024, 4) void k_lstm1(
    const float* __restrict__ x,
    const float* __restrict__ wih_f, const float* __restrict__ whh_f,
    const float* __restrict__ bih_f, const float* __restrict__ bhh_f,
    const float* __restrict__ wih_b, const float* __restrict__ whh_b,
    const float* __restrict__ bih_b, const float* __restrict__ bhh_b,
    unsigned short* __restrict__ y1)
{
    __shared__ short hB_hi[2][1536];   // 96 k x 16 batch, frag order, dbuf

    const int tb  = blockIdx.x & 127;
    const int dir = blockIdx.x >> 7;
    const int b0  = tb << 4;
    const float* wih = dir ? wih_b : wih_f;
    const float* whh = dir ? whh_b : whh_f;
    const float* bih = dir ? bih_b : bih_f;
    const float* bhh = dir ? bhh_b : bhh_f;

    const int tid  = threadIdx.x;
    const int wv   = tid >> 6;
    const int lane = tid & 63;
    const int n    = lane & 15;
    const int quad = lane >> 4;
    const int NT1  = (wv < 2) ? 2 : 1;   // tiles this wave owns

    // ---- W-side (A-operand) preload, hi+lo bf16 ----
    short8 whi[2][3], wlo[2][3];
    const int g_ = n & 3;
#pragma unroll
    for (int tt = 0; tt < 2; ++tt) {
        if (tt < NT1) {
            const int p  = wv + 16 * tt;
            const int uu = 4 * p + (n >> 2);
#pragma unroll
            for (int q = 0; q < 3; ++q) {
#pragma unroll
                for (int j = 0; j < 8; ++j) {
                    int k = q * 32 + quad * 8 + j;
                    float v = 0.0f;
                    if (uu < H1) {
                        int row = g_ * H1 + uu;
                        if (k < H1)        v = whh[row * H1 + k];
                        else if (k < 80)   v = wih[row * Fz + (k - H1)];
                        else if (k == 80)  v = bih[row] + bhh[row];
                    }
                    unsigned short hi = f2bf(v);
                    unsigned short lo = f2bf(v - bf2f(hi));
                    whi[tt][q][j] = (short)hi;
                    wlo[tt][q][j] = (short)lo;
                }
            }
        }
    }

    // ---- init LDS ----
    for (int e = tid; e < 1536; e += 1024) {
        hB_hi[0][e] = 0; hB_hi[1][e] = 0;
    }
    __syncthreads();
    if (tid < 16) {
        int off = 1280 + tid * 8;       // frag_off(tid, 80)
        hB_hi[0][off] = (short)0x3F80;  // bf16(1.0) bias const
        hB_hi[1][off] = (short)0x3F80;
    }

    // ---- stagers: es in [0,160) -> (m, f), threads 864..1023 ----
    const int es = tid - 864;
    const bool stg = (es >= 0 && es < 160);
    int sm = 0, sf = 0;
    if (stg) { sm = es / Fz; sf = es % Fz; }

    const int tstep = dir ? -1 : 1;
    const int t0    = dir ? (Tz - 1) : 0;

    // prologue: stage x(t0) into buf 0; preload x(t1) into regs
    float xv = 0.0f;
    if (stg) {
        float v = x[((size_t)(b0 + sm) * Tz + t0) * Fz + sf];
        hB_hi[0][frag_off(sm, H1 + sf)] = (short)f2bf(v);
        xv = x[((size_t)(b0 + sm) * Tz + t0 + tstep) * Fz + sf];
    }
    // strided pointers (advance by tstep*stride per step)
    const float* xp = x + ((size_t)(b0 + sm) * Tz + t0 + 2 * tstep) * Fz + sf;
    const ptrdiff_t xinc = (ptrdiff_t)tstep * Fz;
    unsigned short* yp = y1 + (((size_t)t0 * 128 + tb) * 140 + dir * H1) * 16 + n;
    const ptrdiff_t yinc = (ptrdiff_t)tstep * (140 * 128 * 16);

    // hoisted LDS write offsets (loop-invariant)
    const int xoff = frag_off(sm, H1 + sf);
    int hoff[2];
#pragma unroll
    for (int tt = 0; tt < 2; ++tt) hoff[tt] = frag_off(n, 4 * (wv + 16 * tt) + quad);

    float cst[2];
    cst[0] = 0.0f; cst[1] = 0.0f;

    // one step; pp is a literal at each call site -> all LDS addrs invariant
    auto body = [&](int step, const int pp) __attribute__((always_inline)) {
        sync_lds();   // buf[pp] complete, buf[pp^1] free (LDS-only barrier)

        if (stg && step + 1 < Tz) {
            hB_hi[pp ^ 1][xoff] = (short)f2bf(xv);
        }
        if (stg && step + 2 < Tz) {
            xv = *xp;
        }

        short8 bhi[3];
#pragma unroll
        for (int q = 0; q < 3; ++q)
            bhi[q] = *(const short8*)&hB_hi[pp][q * 512 + lane * 8];

        // merged hi/lo chain: single acc per tile (saves 4 movs + 4 adds)
        float4v acc[2];
#pragma unroll
        for (int tt = 0; tt < 2; ++tt) acc[tt] = (float4v){0.f, 0.f, 0.f, 0.f};
#pragma unroll
        for (int tt = 0; tt < 2; ++tt) {
            if (tt < NT1) {
                acc[tt] = MFMA16(whi[tt][0], bhi[0], acc[tt]);
                acc[tt] = MFMA16(wlo[tt][0], bhi[0], acc[tt]);
                acc[tt] = MFMA16(whi[tt][1], bhi[1], acc[tt]);
                acc[tt] = MFMA16(wlo[tt][1], bhi[1], acc[tt]);
                acc[tt] = MFMA16(whi[tt][2], bhi[2], acc[tt]);
                acc[tt] = MFMA16(wlo[tt][2], bhi[2], acc[tt]);
            }
        }

#pragma unroll
        for (int tt = 0; tt < 2; ++tt) {
            if (tt < NT1) {
                const int u = 4 * (wv + 16 * tt) + quad;
                if (u < H1) {
                    float h = lstm_gate_h(acc[tt][0], acc[tt][1],
                                          acc[tt][2], acc[tt][3], cst[tt]);
                    unsigned short hh = f2bf(h);
                    hB_hi[pp ^ 1][hoff[tt]] = (short)hh;
                    yp[u * 16] = hh;
                }
            }
        }
        xp += xinc;
        yp += yinc;
    };

    for (int step = 0; step < Tz; step += 2) {
        body(step, 0);
        body(step + 1, 1);
    }
}

// ---------------------------------------------------------------------------
// Layer 2 (MFMA, D = W x h): input 140 (bf16 y1 [T][128][140][16]), hidden 21.
// [r0 structure + diet] Grid 256 = 2 dir x 128 tiles of 16 rows. 512 thr = 8
// waves: waves 0..5 compute tile p = wv (u = 4p+quad); threads 232..511
// stage x (16B vector loads). K: 0..20 = h, 21 = bias, 32..171 = x.
// h/x hi-only; W-lo for chunk 0 only: 7 MFMA/wave, now one merged chain.
// Common-denominator gate epilogue (2 divisions). LDS-only barrier.
// ---------------------------------------------------------------------------
__global__ __launch_bounds__(512, 2) void k_lstm2(
    const unsigned short* __restrict__ y1,
    const float* __restrict__ wih_f, const float* __restrict__ whh_f,
    const float* __restrict__ bih_f, const float* __restrict__ bhh_f,
    const float* __restrict__ wih_b, const float* __restrict__ whh_b,
    const float* __restrict__ bih_b, const float* __restrict__ bhh_b,
    unsigned short* __restrict__ y2)   // [B][T][42] bf16
{
    __shared__ short hB_hi[2][3072];   // 192 k x 16 batch

    const int tb  = blockIdx.x & 127;
    const int dir = blockIdx.x >> 7;
    const int b0  = tb << 4;
    const float* wih = dir ? wih_b : wih_f;
    const float* whh = dir ? whh_b : whh_f;
    const float* bih = dir ? bih_b : bih_f;
    const float* bhh = dir ? bhh_b : bhh_f;

    const int tid  = threadIdx.x;
    const int wv   = tid >> 6;
    const int lane = tid & 63;
    const int n    = lane & 15;
    const int quad = lane >> 4;
    const bool comp = (wv < 6);

    // ---- W-side preload (waves 0..5): hi all chunks, lo chunk 0 ----
    short8 whi[6], wlo0;
    const int g_ = n & 3;
    if (comp) {
        const int uu = 4 * wv + (n >> 2);
#pragma unroll
        for (int q = 0; q < 6; ++q) {
#pragma unroll
            for (int j = 0; j < 8; ++j) {
                int k = q * 32 + quad * 8 + j;
                float v = 0.0f;
                if (uu < H2) {
                    int row = g_ * H2 + uu;
                    if (k < H2)                   v = whh[row * H2 + k];
                    else if (k == 21)             v = bih[row] + bhh[row];
                    else if (k >= 32 && k < 172)  v = wih[row * 140 + (k - 32)];
                }
                unsigned short hi = f2bf(v);
                whi[q][j] = (short)hi;
                if (q == 0) wlo0[j] = (short)f2bf(v - bf2f(hi));
            }
        }
    }

    // ---- init LDS ----
    for (int e = tid; e < 3072; e += 512) { hB_hi[0][e] = 0; hB_hi[1][e] = 0; }
    __syncthreads();
    if (tid < 16) {
        int off = frag_off(tid, 21);
        hB_hi[0][off] = (short)0x3F80;   // bias const 1.0
        hB_hi[1][off] = (short)0x3F80;
    }

    // ---- stager threads: es in [0,280); each loads 16B (8 ushorts) ----
    const int es = tid - 232;
    const bool stg = (es >= 0 && es < 280);

    const int tstep = dir ? -1 : 1;
    const int t0    = dir ? (Tz - 1) : 0;

    // prologue: stage x(t0) into buf 0; preload x(t1)
    short8 xr = (short8){0,0,0,0,0,0,0,0};
    if (stg) {
        short8 v = *(const short8*)(y1 + ((size_t)t0 * 128 + tb) * 2240 + es * 8);
#pragma unroll
        for (int j = 0; j < 8; ++j) {
            int idx = es * 8 + j;
            hB_hi[0][frag_off(idx & 15, 32 + (idx >> 4))] = v[j];
        }
        xr = *(const short8*)(y1 + ((size_t)(t0 + tstep) * 128 + tb) * 2240 + es * 8);
    }
    // strided pointers
    const unsigned short* srcp =
        y1 + ((size_t)(t0 + 2 * tstep) * 128 + tb) * 2240 + es * 8;
    const ptrdiff_t sinc = (ptrdiff_t)tstep * (128 * 2240);
    unsigned short* yp2 = y2 + ((size_t)(b0 + n) * Tz + t0) * 42 + dir * H2;
    const ptrdiff_t yinc = (ptrdiff_t)tstep * 42;

    // hoisted LDS offsets
    int xoffs[8];
#pragma unroll
    for (int j = 0; j < 8; ++j) {
        int idx = es * 8 + j;
        xoffs[j] = frag_off(idx & 15, 32 + (idx >> 4));
    }
    const int u     = 4 * wv + quad;
    const int hoffc = frag_off(n, (u < H2) ? u : 0);

    float cst = 0.0f;

    auto body = [&](int step, const int pp) __attribute__((always_inline)) {
        sync_lds();   // LDS-only barrier

        if (stg && step + 1 < Tz) {
#pragma unroll
            for (int j = 0; j < 8; ++j)
                hB_hi[pp ^ 1][xoffs[j]] = xr[j];
        }
        if (stg && step + 2 < Tz) {
            xr = *(const short8*)srcp;
        }

        if (comp) {
            short8 bhi[6];
#pragma unroll
            for (int q = 0; q < 6; ++q)
                bhi[q] = *(const short8*)&hB_hi[pp][q * 512 + lane * 8];

            // merged chain: single acc (saves 4 movs + 4 adds)
            float4v acc = (float4v){0.f, 0.f, 0.f, 0.f};
            acc = MFMA16(whi[0], bhi[0], acc);
            acc = MFMA16(wlo0,   bhi[0], acc);
            acc = MFMA16(whi[1], bhi[1], acc);
            acc = MFMA16(whi[2], bhi[2], acc);
            acc = MFMA16(whi[3], bhi[3], acc);
            acc = MFMA16(whi[4], bhi[4], acc);
            acc = MFMA16(whi[5], bhi[5], acc);

            if (u < H2) {
                float h = lstm_gate_h(acc[0], acc[1], acc[2], acc[3], cst);
                unsigned short hh = f2bf(h);
                hB_hi[pp ^ 1][hoffc] = (short)hh;
                yp2[u] = hh;
            }
        }
        srcp += sinc;
        yp2  += yinc;
    };

    for (int step = 0; step < Tz; step += 2) {
        body(step, 0);
        body(step + 1, 1);
    }
}

// ---------------------------------------------------------------------------
// Dense head: thread per (b,t). Weights via uniform scalar loads.
// ---------------------------------------------------------------------------
__global__ __launch_bounds__(256) void k_dense(
    const unsigned short* __restrict__ y2,
    const float* __restrict__ wd1, const float* __restrict__ bd1,
    const float* __restrict__ wd2, const float* __restrict__ bd2,
    const float* __restrict__ wo,  const float* __restrict__ bo,
    float* __restrict__ out)
{
    int idx = blockIdx.x * 256 + threadIdx.x;
    if (idx >= Bz * Tz) return;
    const unsigned int* row = (const unsigned int*)&y2[(size_t)idx * 42];

    float v[42];
#pragma unroll
    for (int j = 0; j < 21; ++j) {
        unsigned int p = row[j];
        v[2 * j]     = bf2f((unsigned short)(p & 0xFFFFu));
        v[2 * j + 1] = bf2f((unsigned short)(p >> 16));
    }

    float h1[30];
#pragma unroll
    for (int o = 0; o < 30; ++o) {
        float s = bd1[o];
#pragma unroll
        for (int j = 0; j < 42; ++j) s = fmaf(v[j], wd1[o * 42 + j], s);
        h1[o] = fmaxf(s, 0.0f);
    }
    float outv = bo[0];
#pragma unroll
    for (int o = 0; o < 20; ++o) {
        float s = bd2[o];
#pragma unroll
        for (int j = 0; j < 30; ++j) s = fmaf(h1[j], wd2[o * 30 + j], s);
        outv = fmaf(fmaxf(s, 0.0f), wo[o], outv);
    }
    out[idx] = outv;
}

// ---------------------------------------------------------------------------
extern "C" void kernel_launch(void* const* d_in, const int* in_sizes, int n_in,
                              void* d_out, int out_size, void* d_ws, size_t ws_size,
                              hipStream_t stream)
{
    const float* x      = (const float*)d_in[0];
    const float* w1f_ih = (const float*)d_in[1];
    const float* w1f_hh = (const float*)d_in[2];
    const float* b1f_ih = (const float*)d_in[3];
    const float* b1f_hh = (const float*)d_in[4];
    const float* w1b_ih = (const float*)d_in[5];
    const float* w1b_hh = (const float*)d_in[6];
    const float* b1b_ih = (const float*)d_in[7];
    const float* b1b_hh = (const float*)d_in[8];
    const float* w2f_ih = (const float*)d_in[9];
    const float* w2f_hh = (const float*)d_in[10];
    const float* b2f_ih = (const float*)d_in[11];
    const float* b2f_hh = (const float*)d_in[12];
    const float* w2b_ih = (const float*)d_in[13];
    const float* w2b_hh = (const float*)d_in[14];
    const float* b2b_ih = (const float*)d_in[15];
    const float* b2b_hh = (const float*)d_in[16];
    const float* wd1    = (const float*)d_in[17];
    const float* bd1    = (const float*)d_in[18];
    const float* wd2    = (const float*)d_in[19];
    const float* bd2    = (const float*)d_in[20];
    const float* wo     = (const float*)d_in[21];
    const float* bo     = (const float*)d_in[22];
    float* out = (float*)d_out;

    // Workspace: y1 bf16 [T][128][140][16] (192.7 MB) + y2 bf16 [B][T][42] (57.8 MB)
    const size_t y1_elems = (size_t)Tz * 128 * 2240;
    const size_t y2_elems = (size_t)Bz * Tz * 42;
    if (ws_size < (y1_elems + y2_elems) * 2) return;

    unsigned short* y1 = (unsigned short*)d_ws;
    unsigned short* y2 = y1 + y1_elems;

    hipLaunchKernelGGL(k_lstm1, dim3(256), dim3(1024), 0, stream,
                       x, w1f_ih, w1f_hh, b1f_ih, b1f_hh,
                       w1b_ih, w1b_hh, b1b_ih, b1b_hh, y1);
    hipLaunchKernelGGL(k_lstm2, dim3(256), dim3(512), 0, stream,
                       y1, w2f_ih, w2f_hh, b2f_ih, b2f_hh,
                       w2b_ih, w2b_hh, b2b_ih, b2b_hh, y2);
    hipLaunchKernelGGL(k_dense, dim3((Bz * Tz + 255) / 256), dim3(256), 0, stream,
                       y2, wd1, bd1, wd2, bd2, wo, bo, out);
}

// Round 17
// 573.942 us; speedup vs baseline: 3.3089x; 1.0142x over previous
//
#include <hip/hip_runtime.h>

// Problem constants
#define Bz 2048
#define Tz 336
#define Fz 10
#define H1 70
#define H2 21

typedef __attribute__((ext_vector_type(8))) short short8;   // 8 bf16 = 4 VGPR
typedef __attribute__((ext_vector_type(4))) float float4v;  // MFMA acc

#define MFMA16(a, b, c) __builtin_amdgcn_mfma_f32_16x16x32_bf16((a), (b), (c), 0, 0, 0)

// LDS-only barrier (composable-kernel idiom): orders LDS across the block
// WITHOUT draining vmcnt — __syncthreads() would stall on the y1/y2 global
// stores (never read in-kernel) every step (~200-900 cyc store-ack, m126).
__device__ __forceinline__ void sync_lds() {
    asm volatile("s_waitcnt lgkmcnt(0)\n\ts_barrier" ::: "memory");
}

// Manual RNE f32->bf16 (validated). r14: v_cvt_pk_bf16_f32 regressed absmax
// 10x (biased rounding compounds through the 336-step recurrence).
__device__ __forceinline__ unsigned short f2bf(float v) {
    unsigned int u = __float_as_uint(v);
    u += 0x7FFFu + ((u >> 16) & 1u);
    return (unsigned short)(u >> 16);
}
__device__ __forceinline__ float bf2f(unsigned short s) {
    return __uint_as_float(((unsigned int)s) << 16);
}

// [r12-VALIDATED gate epilogue — exp-domain, true division.]
// r14/r15 POST-MORTEM: the diet2 numeric variants (exp2-domain pre-scaled
// weights + raw v_rcp) regressed absmax 0.98e-3 -> ~9e-3 (fail); reverting
// cvt_pk alone didn't fix it. This round bisects: numerics fully reverted
// to this r12 form (measured absmax 0.98e-3), keeping only the bit-identical
// frag-order y1 layout change.
//   cn = sig(f)*c + sig(i)*tanh(g);  h = sig(o)*tanh(cn)
// via a=e^-f, b=e^-i, d=e^2g:  cn = (c*pb*pd + pa*(d-1)) / (pa*pb*pd)
// 5 exp + 2 true divisions (common-denominator form).
__device__ __forceinline__ float lstm_gate_h(float gi, float gf, float gc,
                                             float go, float& cst) {
    float a  = __expf(-gf);
    float b  = __expf(-gi);
    float d  = __expf(2.0f * gc);
    float pa = 1.0f + a;
    float pb = 1.0f + b;
    float pd = d + 1.0f;
    float t1 = pb * pd;
    float num = fmaf(pa, d - 1.0f, cst * t1);
    float cn  = num / (pa * t1);
    float e2  = __expf(-go);
    float f2  = __expf(2.0f * cn);
    float h   = (f2 - 1.0f) / ((1.0f + e2) * (f2 + 1.0f));
    cst = cn;
    return h;
}

// Fragment-order LDS offset (in shorts) for (col m, k):
// (m, k) lives at ((k>>3)*16 + m)*8 + (k&7)
__device__ __forceinline__ int frag_off(int m, int k) {
    return (k >> 3) * 128 + m * 8 + (k & 7);
}

// ---------------------------------------------------------------------------
// Layer 1 (MFMA, D = W x h): input F=10, hidden 70.
// [r12 numerics + frag-order y1 only]
// Grid 256 = 2 dir x 128 tiles of 16 batch rows. 1024 threads = 16 waves.
// 18 M-tiles: wave w owns tile w; waves 0,1 also own tiles 16,17.
//   K: 0..69 = h, 70..79 = x, 80 = bias slot (B col 1.0), 81..95 = 0.
// h bf16 hi-only in LDS; W hi+lo in registers (6 MFMA/tile, merged chain).
// ONE LDS-only barrier per step, double-buffered B-LDS, x prefetch depth 2,
// step loop unrolled x2 (pp literal), strided pointers.
// y1 layout: [T][128][2304] bf16, frag-ordered for k=32..171 (slot =
// frag_off(n, 32+dir*70+u) - 512); k=172..175 slots are holes (never
// written; lstm2 stagers zero them in-register).
// ---------------------------------------------------------------------------
__global__ __launch_bounds__(1024, 4) void k_lstm1(
    const float* __restrict__ x,
    const float* __restrict__ wih_f, const float* __restrict__ whh_f,
    const float* __restrict__ bih_f, const float* __restrict__ bhh_f,
    const float* __restrict__ wih_b, const float* __restrict__ whh_b,
    const float* __restrict__ bih_b, const float* __restrict__ bhh_b,
    unsigned short* __restrict__ y1)
{
    __shared__ short hB_hi[2][1536];   // 96 k x 16 batch, frag order, dbuf

    const int tb  = blockIdx.x & 127;
    const int dir = blockIdx.x >> 7;
    const int b0  = tb << 4;
    const float* wih = dir ? wih_b : wih_f;
    const float* whh = dir ? whh_b : whh_f;
    const float* bih = dir ? bih_b : bih_f;
    const float* bhh = dir ? bhh_b : bhh_f;

    const int tid  = threadIdx.x;
    const int wv   = tid >> 6;
    const int lane = tid & 63;
    const int n    = lane & 15;
    const int quad = lane >> 4;
    const int NT1  = (wv < 2) ? 2 : 1;   // tiles this wave owns

    // ---- W-side (A-operand) preload, hi+lo bf16 (UNSCALED — r12 domain) ----
    short8 whi[2][3], wlo[2][3];
    const int g_ = n & 3;                               // 0=i 1=f 2=g 3=o
#pragma unroll
    for (int tt = 0; tt < 2; ++tt) {
        if (tt < NT1) {
            const int p  = wv + 16 * tt;
            const int uu = 4 * p + (n >> 2);
#pragma unroll
            for (int q = 0; q < 3; ++q) {
#pragma unroll
                for (int j = 0; j < 8; ++j) {
                    int k = q * 32 + quad * 8 + j;
                    float v = 0.0f;
                    if (uu < H1) {
                        int row = g_ * H1 + uu;
                        if (k < H1)        v = whh[row * H1 + k];
                        else if (k < 80)   v = wih[row * Fz + (k - H1)];
                        else if (k == 80)  v = bih[row] + bhh[row];
                    }
                    unsigned short hi = f2bf(v);
                    unsigned short lo = f2bf(v - bf2f(hi));
                    whi[tt][q][j] = (short)hi;
                    wlo[tt][q][j] = (short)lo;
                }
            }
        }
    }

    // ---- init LDS ----
    for (int e = tid; e < 1536; e += 1024) {
        hB_hi[0][e] = 0; hB_hi[1][e] = 0;
    }
    __syncthreads();
    if (tid < 16) {
        int off = 1280 + tid * 8;       // frag_off(tid, 80)
        hB_hi[0][off] = (short)0x3F80;  // bf16(1.0) bias const
        hB_hi[1][off] = (short)0x3F80;
    }

    // ---- stagers: es in [0,160) -> (m, f), threads 864..1023 ----
    const int es = tid - 864;
    const bool stg = (es >= 0 && es < 160);
    int sm = 0, sf = 0;
    if (stg) { sm = es / Fz; sf = es % Fz; }

    const int tstep = dir ? -1 : 1;
    const int t0    = dir ? (Tz - 1) : 0;

    // prologue: stage x(t0) into buf 0; preload x(t1) into regs
    float xv = 0.0f;
    if (stg) {
        float v = x[((size_t)(b0 + sm) * Tz + t0) * Fz + sf];
        hB_hi[0][frag_off(sm, H1 + sf)] = (short)f2bf(v);
        xv = x[((size_t)(b0 + sm) * Tz + t0 + tstep) * Fz + sf];
    }
    // strided pointers (advance by tstep*stride per step)
    const float* xp = x + ((size_t)(b0 + sm) * Tz + t0 + 2 * tstep) * Fz + sf;
    const ptrdiff_t xinc = (ptrdiff_t)tstep * Fz;
    unsigned short* ypB = y1 + (size_t)(t0 * 128 + tb) * 2304;
    const ptrdiff_t yinc = (ptrdiff_t)tstep * (128 * 2304);

    // hoisted LDS/global write offsets (loop-invariant)
    const int xoff = frag_off(sm, H1 + sf);
    int hoff[2], yoff[2];
#pragma unroll
    for (int tt = 0; tt < 2; ++tt) {
        const int u = 4 * (wv + 16 * tt) + quad;
        hoff[tt] = frag_off(n, u);
        const int K = 32 + dir * H1 + u;               // lstm2 frag k-index
        yoff[tt] = ((K >> 3) * 16 + n) * 8 + (K & 7) - 512;
    }

    float cst[2];
    cst[0] = 0.0f; cst[1] = 0.0f;

    // one step; pp is a literal at each call site -> all LDS addrs invariant
    auto body = [&](int step, const int pp) __attribute__((always_inline)) {
        sync_lds();   // buf[pp] complete, buf[pp^1] free (LDS-only barrier)

        if (stg && step + 1 < Tz) {
            hB_hi[pp ^ 1][xoff] = (short)f2bf(xv);
        }
        if (stg && step + 2 < Tz) {
            xv = *xp;
        }

        short8 bhi[3];
#pragma unroll
        for (int q = 0; q < 3; ++q)
            bhi[q] = *(const short8*)&hB_hi[pp][q * 512 + lane * 8];

        // merged hi/lo chain: single acc per tile
        float4v acc[2];
#pragma unroll
        for (int tt = 0; tt < 2; ++tt) acc[tt] = (float4v){0.f, 0.f, 0.f, 0.f};
#pragma unroll
        for (int tt = 0; tt < 2; ++tt) {
            if (tt < NT1) {
                acc[tt] = MFMA16(whi[tt][0], bhi[0], acc[tt]);
                acc[tt] = MFMA16(wlo[tt][0], bhi[0], acc[tt]);
                acc[tt] = MFMA16(whi[tt][1], bhi[1], acc[tt]);
                acc[tt] = MFMA16(wlo[tt][1], bhi[1], acc[tt]);
                acc[tt] = MFMA16(whi[tt][2], bhi[2], acc[tt]);
                acc[tt] = MFMA16(wlo[tt][2], bhi[2], acc[tt]);
            }
        }

#pragma unroll
        for (int tt = 0; tt < 2; ++tt) {
            if (tt < NT1) {
                const int u = 4 * (wv + 16 * tt) + quad;
                if (u < H1) {
                    float h = lstm_gate_h(acc[tt][0], acc[tt][1],
                                          acc[tt][2], acc[tt][3], cst[tt]);
                    unsigned short hh = f2bf(h);
                    hB_hi[pp ^ 1][hoff[tt]] = (short)hh;
                    ypB[yoff[tt]] = hh;
                }
            }
        }
        xp  += xinc;
        ypB += yinc;
    };

    for (int step = 0; step < Tz; step += 2) {
        body(step, 0);
        body(step + 1, 1);
    }
}

// ---------------------------------------------------------------------------
// Layer 2 (MFMA, D = W x h): input 140 (bf16 y1 [T][128][2304] FRAG-ORDER),
// hidden 21.  [r12 numerics + 16B-copy staging]
// Grid 256 = 2 dir x 128 tiles of 16 rows. 512 thr = 8 waves: waves 0..5
// compute tile p = wv (u = 4p+quad); threads 224..511 stage x: y1 is
// frag-ordered, so each stager is ONE 16B load + ONE ds_write_b128 (was 8
// scattered ds_write_b16 + addr math). Stagers es>=272 zero the k=172..175
// hole lanes in-register (0*NaN = NaN guard). K: 0..20 = h, 21 = bias,
// 32..171 = x. h/x hi-only; W-lo chunk 0 only: 7 MFMA merged chain.
// r12 gate epilogue. LDS-only barrier, dbuf, prefetch depth 2, x2 unroll.
// ---------------------------------------------------------------------------
__global__ __launch_bounds__(512, 2) void k_lstm2(
    const unsigned short* __restrict__ y1,
    const float* __restrict__ wih_f, const float* __restrict__ whh_f,
    const float* __restrict__ bih_f, const float* __restrict__ bhh_f,
    const float* __restrict__ wih_b, const float* __restrict__ whh_b,
    const float* __restrict__ bih_b, const float* __restrict__ bhh_b,
    unsigned short* __restrict__ y2)   // [B][T][42] bf16
{
    __shared__ short hB_hi[2][3072];   // 192 k x 16 batch

    const int tb  = blockIdx.x & 127;
    const int dir = blockIdx.x >> 7;
    const int b0  = tb << 4;
    const float* wih = dir ? wih_b : wih_f;
    const float* whh = dir ? whh_b : whh_f;
    const float* bih = dir ? bih_b : bih_f;
    const float* bhh = dir ? bhh_b : bhh_f;

    const int tid  = threadIdx.x;
    const int wv   = tid >> 6;
    const int lane = tid & 63;
    const int n    = lane & 15;
    const int quad = lane >> 4;
    const bool comp = (wv < 6);

    // ---- W-side preload (waves 0..5): hi all chunks, lo chunk 0 (UNSCALED) ----
    short8 whi[6], wlo0;
    const int g_ = n & 3;
    if (comp) {
        const int uu = 4 * wv + (n >> 2);
#pragma unroll
        for (int q = 0; q < 6; ++q) {
#pragma unroll
            for (int j = 0; j < 8; ++j) {
                int k = q * 32 + quad * 8 + j;
                float v = 0.0f;
                if (uu < H2) {
                    int row = g_ * H2 + uu;
                    if (k < H2)                   v = whh[row * H2 + k];
                    else if (k == 21)             v = bih[row] + bhh[row];
                    else if (k >= 32 && k < 172)  v = wih[row * 140 + (k - 32)];
                }
                unsigned short hi = f2bf(v);
                whi[q][j] = (short)hi;
                if (q == 0) wlo0[j] = (short)f2bf(v - bf2f(hi));
            }
        }
    }

    // ---- init LDS ----
    for (int e = tid; e < 3072; e += 512) { hB_hi[0][e] = 0; hB_hi[1][e] = 0; }
    __syncthreads();
    if (tid < 16) {
        int off = frag_off(tid, 21);
        hB_hi[0][off] = (short)0x3F80;   // bias const 1.0
        hB_hi[1][off] = (short)0x3F80;
    }

    // ---- stagers: es in [0,288); threads 224..511; 16B frag-order copy ----
    const int es = tid - 224;
    const bool stg = (es >= 0 && es < 288);
    const bool hole = (es >= 272);       // last k-block: lanes 4..7 = hole

    const int tstep = dir ? -1 : 1;
    const int t0    = dir ? (Tz - 1) : 0;

    // prologue: stage x(t0) into buf 0; preload x(t1)
    short8 xr = (short8){0,0,0,0,0,0,0,0};
    if (stg) {
        short8 v = *(const short8*)(y1 + ((size_t)t0 * 128 + tb) * 2304 + es * 8);
        if (hole) { v[4] = 0; v[5] = 0; v[6] = 0; v[7] = 0; }
        *(short8*)&hB_hi[0][512 + es * 8] = v;
        xr = *(const short8*)(y1 + ((size_t)(t0 + tstep) * 128 + tb) * 2304 + es * 8);
    }
    // strided pointers
    const unsigned short* srcp =
        y1 + ((size_t)(t0 + 2 * tstep) * 128 + tb) * 2304 + es * 8;
    const ptrdiff_t sinc = (ptrdiff_t)tstep * (128 * 2304);
    unsigned short* yp2 = y2 + ((size_t)(b0 + n) * Tz + t0) * 42 + dir * H2;
    const ptrdiff_t yinc = (ptrdiff_t)tstep * 42;

    const int u     = 4 * wv + quad;
    const int hoffc = frag_off(n, (u < H2) ? u : 0);

    float cst = 0.0f;

    auto body = [&](int step, const int pp) __attribute__((always_inline)) {
        sync_lds();   // LDS-only barrier

        if (stg && step + 1 < Tz) {
            short8 v = xr;
            if (hole) { v[4] = 0; v[5] = 0; v[6] = 0; v[7] = 0; }
            *(short8*)&hB_hi[pp ^ 1][512 + es * 8] = v;
        }
        if (stg && step + 2 < Tz) {
            xr = *(const short8*)srcp;
        }

        if (comp) {
            short8 bhi[6];
#pragma unroll
            for (int q = 0; q < 6; ++q)
                bhi[q] = *(const short8*)&hB_hi[pp][q * 512 + lane * 8];

            // merged chain: single acc
            float4v acc = (float4v){0.f, 0.f, 0.f, 0.f};
            acc = MFMA16(whi[0], bhi[0], acc);
            acc = MFMA16(wlo0,   bhi[0], acc);
            acc = MFMA16(whi[1], bhi[1], acc);
            acc = MFMA16(whi[2], bhi[2], acc);
            acc = MFMA16(whi[3], bhi[3], acc);
            acc = MFMA16(whi[4], bhi[4], acc);
            acc = MFMA16(whi[5], bhi[5], acc);

            if (u < H2) {
                float h = lstm_gate_h(acc[0], acc[1], acc[2], acc[3], cst);
                unsigned short hh = f2bf(h);
                hB_hi[pp ^ 1][hoffc] = (short)hh;
                yp2[u] = hh;
            }
        }
        srcp += sinc;
        yp2  += yinc;
    };

    for (int step = 0; step < Tz; step += 2) {
        body(step, 0);
        body(step + 1, 1);
    }
}

// ---------------------------------------------------------------------------
// Dense head: thread per (b,t). Weights via uniform scalar loads.
// ---------------------------------------------------------------------------
__global__ __launch_bounds__(256) void k_dense(
    const unsigned short* __restrict__ y2,
    const float* __restrict__ wd1, const float* __restrict__ bd1,
    const float* __restrict__ wd2, const float* __restrict__ bd2,
    const float* __restrict__ wo,  const float* __restrict__ bo,
    float* __restrict__ out)
{
    int idx = blockIdx.x * 256 + threadIdx.x;
    if (idx >= Bz * Tz) return;
    const unsigned int* row = (const unsigned int*)&y2[(size_t)idx * 42];

    float v[42];
#pragma unroll
    for (int j = 0; j < 21; ++j) {
        unsigned int p = row[j];
        v[2 * j]     = bf2f((unsigned short)(p & 0xFFFFu));
        v[2 * j + 1] = bf2f((unsigned short)(p >> 16));
    }

    float h1[30];
#pragma unroll
    for (int o = 0; o < 30; ++o) {
        float s = bd1[o];
#pragma unroll
        for (int j = 0; j < 42; ++j) s = fmaf(v[j], wd1[o * 42 + j], s);
        h1[o] = fmaxf(s, 0.0f);
    }
    float outv = bo[0];
#pragma unroll
    for (int o = 0; o < 20; ++o) {
        float s = bd2[o];
#pragma unroll
        for (int j = 0; j < 30; ++j) s = fmaf(h1[j], wd2[o * 30 + j], s);
        outv = fmaf(fmaxf(s, 0.0f), wo[o], outv);
    }
    out[idx] = outv;
}

// ---------------------------------------------------------------------------
extern "C" void kernel_launch(void* const* d_in, const int* in_sizes, int n_in,
                              void* d_out, int out_size, void* d_ws, size_t ws_size,
                              hipStream_t stream)
{
    const float* x      = (const float*)d_in[0];
    const float* w1f_ih = (const float*)d_in[1];
    const float* w1f_hh = (const float*)d_in[2];
    const float* b1f_ih = (const float*)d_in[3];
    const float* b1f_hh = (const float*)d_in[4];
    const float* w1b_ih = (const float*)d_in[5];
    const float* w1b_hh = (const float*)d_in[6];
    const float* b1b_ih = (const float*)d_in[7];
    const float* b1b_hh = (const float*)d_in[8];
    const float* w2f_ih = (const float*)d_in[9];
    const float* w2f_hh = (const float*)d_in[10];
    const float* b2f_ih = (const float*)d_in[11];
    const float* b2f_hh = (const float*)d_in[12];
    const float* w2b_ih = (const float*)d_in[13];
    const float* w2b_hh = (const float*)d_in[14];
    const float* b2b_ih = (const float*)d_in[15];
    const float* b2b_hh = (const float*)d_in[16];
    const float* wd1    = (const float*)d_in[17];
    const float* bd1    = (const float*)d_in[18];
    const float* wd2    = (const float*)d_in[19];
    const float* bd2    = (const float*)d_in[20];
    const float* wo     = (const float*)d_in[21];
    const float* bo     = (const float*)d_in[22];
    float* out = (float*)d_out;

    // Workspace: y1 bf16 [T][128][2304] frag-order (198.2 MB)
    //          + y2 bf16 [B][T][42] (57.8 MB)
    const size_t y1_elems = (size_t)Tz * 128 * 2304;
    const size_t y2_elems = (size_t)Bz * Tz * 42;
    if (ws_size < (y1_elems + y2_elems) * 2) return;

    unsigned short* y1 = (unsigned short*)d_ws;
    unsigned short* y2 = y1 + y1_elems;

    hipLaunchKernelGGL(k_lstm1, dim3(256), dim3(1024), 0, stream,
                       x, w1f_ih, w1f_hh, b1f_ih, b1f_hh,
                       w1b_ih, w1b_hh, b1b_ih, b1b_hh, y1);
    hipLaunchKernelGGL(k_lstm2, dim3(256), dim3(512), 0, stream,
                       y1, w2f_ih, w2f_hh, b2f_ih, b2f_hh,
                       w2b_ih, w2b_hh, b2b_ih, b2b_hh, y2);
    hipLaunchKernelGGL(k_dense, dim3((Bz * Tz + 255) / 256), dim3(256), 0, stream,
                       y2, wd1, bd1, wd2, bd2, wo, bo, out);
}